// Round 1
// baseline (1793.304 us; speedup 1.0000x reference)
//
#include <hip/hip_runtime.h>
#include <math.h>

#define NB 4096
#define DC 256
#define PC 512

// ---------------- K0: transpose protolayer + p2 ----------------
__global__ __launch_bounds__(256) void k_prep(const float* __restrict__ proto,
                                              float* __restrict__ protoT,
                                              float* __restrict__ p2) {
    int p = blockIdx.x;       // 0..511
    int d = threadIdx.x;      // 0..255
    float v = proto[p * DC + d];
    protoT[d * PC + p] = v;
    __shared__ float red[256];
    red[d] = v * v;
    __syncthreads();
    for (int s = 128; s > 0; s >>= 1) {
        if (d < s) red[d] += red[d + s];
        __syncthreads();
    }
    if (d == 0) p2[p] = red[0];
}

// ---------------- K1: encoder convs + prototype distances + softmax + z ----------------
__global__ __launch_bounds__(512) void k_enc_proto(
    const float* __restrict__ x,
    const float* __restrict__ w1, const float* __restrict__ b1,
    const float* __restrict__ w2, const float* __restrict__ b2,
    const float* __restrict__ g2, const float* __restrict__ bt2,
    const float* __restrict__ w3, const float* __restrict__ b3,
    const float* __restrict__ proto, const float* __restrict__ protoT,
    const float* __restrict__ p2,
    float* __restrict__ md_out,    // [B][512]
    float* __restrict__ zg)        // [B][256]
{
    int b = blockIdx.x;
    int t = threadIdx.x;

    __shared__ float xb[784];        // 28x28
    __shared__ float h1[8 * 196];    // 8x14x14
    __shared__ float h2[16 * 49];    // 16x7x7
    __shared__ float h3[256 * 28];   // 256 x 25 (padded to 28)
    __shared__ float x2s[25];
    __shared__ float red[512];
    __shared__ float wbuf[512];

    const float bnr = rsqrtf(1.0f + 1e-5f);

    const float* xg = x + b * 784;
    for (int i = t; i < 784; i += 512) xb[i] = xg[i];
    __syncthreads();

    // conv1: 1->8, k3 s2 p1, 28->14, bias+relu
    for (int o = t; o < 8 * 196; o += 512) {
        int c = o / 196, r = o % 196, y = r / 14, xx = r % 14;
        float acc = b1[c];
        for (int sy = 0; sy < 3; sy++) {
            int iy = 2 * y - 1 + sy;
            if ((unsigned)iy >= 28u) continue;
            for (int sx = 0; sx < 3; sx++) {
                int ix = 2 * xx - 1 + sx;
                if ((unsigned)ix >= 28u) continue;
                acc += w1[c * 9 + sy * 3 + sx] * xb[iy * 28 + ix];
            }
        }
        h1[o] = fmaxf(acc, 0.f);
    }
    __syncthreads();

    // conv2: 8->16, k3 s2 p1, 14->7, bias+bn+relu
    for (int o = t; o < 16 * 49; o += 512) {
        int c = o / 49, r = o % 49, y = r / 7, xx = r % 7;
        float acc = b2[c];
        for (int ci = 0; ci < 8; ci++) {
            for (int sy = 0; sy < 3; sy++) {
                int iy = 2 * y - 1 + sy;
                if ((unsigned)iy >= 14u) continue;
                for (int sx = 0; sx < 3; sx++) {
                    int ix = 2 * xx - 1 + sx;
                    if ((unsigned)ix >= 14u) continue;
                    acc += w2[((c * 8 + ci) * 3 + sy) * 3 + sx] * h1[ci * 196 + iy * 14 + ix];
                }
            }
        }
        float s = g2[c] * bnr;
        h2[o] = fmaxf(acc * s + bt2[c], 0.f);
    }
    __syncthreads();

    // conv3: 16->256, k3 s1 p0, 7->5, bias+relu. 512 threads: (d = t&255, half = t>>8) split ci.
    {
        int d = t & 255, half = t >> 8;
        float acc[25];
#pragma unroll
        for (int i = 0; i < 25; i++) acc[i] = 0.f;
        for (int ci = half * 8; ci < half * 8 + 8; ci++) {
            for (int s = 0; s < 9; s++) {
                int sy = s / 3, sx = s % 3;
                float w = w3[(d * 16 + ci) * 9 + s];
#pragma unroll
                for (int pos = 0; pos < 25; pos++) {
                    int y = pos / 5, xx = pos % 5;
                    acc[pos] += w * h2[ci * 49 + (y + sy) * 7 + (xx + sx)];
                }
            }
        }
        if (half == 1) {
#pragma unroll
            for (int pos = 0; pos < 25; pos++) h3[d * 28 + pos] = acc[pos];
        }
        __syncthreads();
        if (half == 0) {
            float bb = b3[d];
#pragma unroll
            for (int pos = 0; pos < 25; pos++) {
                float v = acc[pos] + h3[d * 28 + pos] + bb;
                h3[d * 28 + pos] = fmaxf(v, 0.f);
            }
        }
        __syncthreads();
    }

    // x2_patch_sum
    if (t < 25) {
        float s = 0.f;
        for (int d = 0; d < 256; d++) {
            float v = h3[d * 28 + t];
            s += v * v;
        }
        x2s[t] = s;
    }
    __syncthreads();

    // distances for prototype p = t; min over 25 positions
    float mind;
    {
        int p = t;
        float acc[25];
#pragma unroll
        for (int i = 0; i < 25; i++) acc[i] = 0.f;
#pragma unroll 2
        for (int d = 0; d < 256; d++) {
            float pv = protoT[d * PC + p];
#pragma unroll
            for (int pos = 0; pos < 25; pos++) {
                acc[pos] += pv * h3[d * 28 + pos];
            }
        }
        float p2v = p2[p];
        mind = 1e30f;
#pragma unroll
        for (int pos = 0; pos < 25; pos++) {
            float dd = x2s[pos] - 2.f * acc[pos] + p2v;
            dd = fmaxf(dd, 0.f);
            mind = fminf(mind, dd);
        }
        md_out[b * PC + p] = mind;
    }

    // softmax over p of (-mind)
    float a = -mind;
    red[t] = a;
    __syncthreads();
    for (int s = 256; s > 0; s >>= 1) {
        if (t < s) red[t] = fmaxf(red[t], red[t + s]);
        __syncthreads();
    }
    float m = red[0];
    __syncthreads();
    float e = expf(a - m);
    red[t] = e;
    __syncthreads();
    for (int s = 256; s > 0; s >>= 1) {
        if (t < s) red[t] += red[t + s];
        __syncthreads();
    }
    float sum = red[0];
    wbuf[t] = e / sum;
    __syncthreads();

    // z[d] = sum_p w[p] * proto[p][d]
    if (t < 256) {
        float acc = 0.f;
        for (int p = 0; p < 512; p++) acc += wbuf[p] * proto[p * DC + t];
        zg[b * DC + t] = acc;
    }
}

// ---------------- K2: zup GEMM  C[4096][6400] = Z[4096][256] * Wup[256][6400], bias+bn+relu ----------------
__global__ __launch_bounds__(256) void k_zup(
    const float* __restrict__ zg, const float* __restrict__ wup,
    const float* __restrict__ bup, const float* __restrict__ gup,
    const float* __restrict__ btup,
    float* __restrict__ zup)
{
    __shared__ float As[32 * 65];   // [k][m] padded
    __shared__ float Bs[32 * 64];   // [k][n]
    int t = threadIdx.x;
    int n0 = blockIdx.x * 64;       // 100 blocks
    int m0 = blockIdx.y * 64;       // 64 blocks
    int tx = t % 16, ty = t / 16;
    float acc[4][4];
#pragma unroll
    for (int i = 0; i < 4; i++)
#pragma unroll
        for (int j = 0; j < 4; j++) acc[i][j] = 0.f;

    for (int k0 = 0; k0 < 256; k0 += 32) {
        for (int i = t; i < 2048; i += 256) {
            int m = i / 32, k = i % 32;
            As[k * 65 + m] = zg[(m0 + m) * 256 + k0 + k];
        }
        for (int i = t; i < 2048; i += 256) {
            int k = i / 64, n = i % 64;
            Bs[k * 64 + n] = wup[(k0 + k) * 6400 + n0 + n];
        }
        __syncthreads();
#pragma unroll 8
        for (int k = 0; k < 32; k++) {
            float a0 = As[k * 65 + ty], a1 = As[k * 65 + ty + 16];
            float a2 = As[k * 65 + ty + 32], a3 = As[k * 65 + ty + 48];
            float b0 = Bs[k * 64 + tx], b1 = Bs[k * 64 + tx + 16];
            float b2 = Bs[k * 64 + tx + 32], b3 = Bs[k * 64 + tx + 48];
            acc[0][0] += a0 * b0; acc[0][1] += a0 * b1; acc[0][2] += a0 * b2; acc[0][3] += a0 * b3;
            acc[1][0] += a1 * b0; acc[1][1] += a1 * b1; acc[1][2] += a1 * b2; acc[1][3] += a1 * b3;
            acc[2][0] += a2 * b0; acc[2][1] += a2 * b1; acc[2][2] += a2 * b2; acc[2][3] += a2 * b3;
            acc[3][0] += a3 * b0; acc[3][1] += a3 * b1; acc[3][2] += a3 * b2; acc[3][3] += a3 * b3;
        }
        __syncthreads();
    }

    const float bnr = rsqrtf(1.0f + 1e-5f);
#pragma unroll
    for (int i = 0; i < 4; i++) {
#pragma unroll
        for (int j = 0; j < 4; j++) {
            int m = m0 + ty + 16 * i, n = n0 + tx + 16 * j;
            int co = n / 25;
            float s = gup[co] * bnr;
            float v = (acc[i][j] + bup[co]) * s + btup[co];
            zup[m * 6400 + n] = fmaxf(v, 0.f);
        }
    }
}

// ---------------- K3: decoder (wd1 + wd2 + wd3 + sigmoid), one block per image ----------------
__global__ __launch_bounds__(256) void k_dec(
    const float* __restrict__ zup,
    const float* __restrict__ wd1, const float* __restrict__ bd1,
    const float* __restrict__ gd1, const float* __restrict__ btd1,
    const float* __restrict__ wd2, const float* __restrict__ bd2,
    const float* __restrict__ gd2, const float* __restrict__ btd2,
    const float* __restrict__ wd3, const float* __restrict__ bd3,
    float* __restrict__ out0)
{
    int b = blockIdx.x, t = threadIdx.x;
    __shared__ float zT[25 * 260];    // [pos][ci] padded to 260
    __shared__ float wT[144 * 36];    // [co*9+s][ci(32-chunk)] padded to 36
    __shared__ float hd1s[16 * 49];
    __shared__ float hd2s[8 * 196];
    __shared__ float w2s[1152];
    __shared__ float w3s[72];

    const float bnr = rsqrtf(1.0f + 1e-5f);

    const float* zgv = zup + b * 6400;
    for (int i = t; i < 6400; i += 256) {
        int ci = i / 25, pos = i % 25;
        zT[pos * 260 + ci] = zgv[i];
    }
    for (int i = t; i < 1152; i += 256) w2s[i] = wd2[i];
    if (t < 72) w3s[t] = wd3[t];

    // wd1: convT 256->16, k3 s1 p0, 5->7
    float acc[4] = {0.f, 0.f, 0.f, 0.f};
    for (int cb = 0; cb < 256; cb += 32) {
        __syncthreads();   // zT ready / previous chunk consumers done
        for (int i = t; i < 32 * 144; i += 256) {
            int ci = i / 144, s = i % 144;
            wT[s * 36 + ci] = wd1[(cb + ci) * 144 + s];
        }
        __syncthreads();
#pragma unroll
        for (int r = 0; r < 4; r++) {
            int o = t + 256 * r;
            if (o >= 784) break;
            int co = o / 49, rr = o % 49, y = rr / 7, xx = rr % 7;
            float a = acc[r];
            int sy0 = y - 4 > 0 ? y - 4 : 0, sy1 = y < 2 ? y : 2;
            for (int sy = sy0; sy <= sy1; sy++) {
                int iy = y - sy;
                int sx0 = xx - 4 > 0 ? xx - 4 : 0, sx1 = xx < 2 ? xx : 2;
                for (int sx = sx0; sx <= sx1; sx++) {
                    int ix = xx - sx;
                    const float* wrow = &wT[(co * 9 + sy * 3 + sx) * 36];
                    const float* zrow = &zT[(iy * 5 + ix) * 260 + cb];
#pragma unroll
                    for (int ci = 0; ci < 32; ci += 4) {
                        float4 wv = *(const float4*)&wrow[ci];
                        float4 zv = *(const float4*)&zrow[ci];
                        a += wv.x * zv.x + wv.y * zv.y + wv.z * zv.z + wv.w * zv.w;
                    }
                }
            }
            acc[r] = a;
        }
    }
    __syncthreads();
#pragma unroll
    for (int r = 0; r < 4; r++) {
        int o = t + 256 * r;
        if (o >= 784) break;
        int co = o / 49;
        float v = (acc[r] + bd1[co]) * (gd1[co] * bnr) + btd1[co];
        hd1s[o] = fmaxf(v, 0.f);
    }
    __syncthreads();

    // wd2: convT 16->8, k3 s2 p1 op1, 7->14
    for (int o = t; o < 8 * 196; o += 256) {
        int co = o / 196, r = o % 196, y = r / 14, xx = r % 14;
        float a = 0.f;
        for (int sy = 0; sy < 3; sy++) {
            int yn = y + 1 - sy;
            if (yn & 1) continue;
            int iy = yn >> 1;
            if ((unsigned)iy >= 7u) continue;
            for (int sx = 0; sx < 3; sx++) {
                int xn = xx + 1 - sx;
                if (xn & 1) continue;
                int ix = xn >> 1;
                if ((unsigned)ix >= 7u) continue;
                for (int ci = 0; ci < 16; ci++)
                    a += w2s[(ci * 8 + co) * 9 + sy * 3 + sx] * hd1s[ci * 49 + iy * 7 + ix];
            }
        }
        float v = (a + bd2[co]) * (gd2[co] * bnr) + btd2[co];
        hd2s[o] = fmaxf(v, 0.f);
    }
    __syncthreads();

    // wd3: convT 8->1, k3 s2 p1 op1, 14->28, bias + sigmoid
    float* og = out0 + b * 784;
    for (int o = t; o < 784; o += 256) {
        int y = o / 28, xx = o % 28;
        float a = bd3[0];
        for (int sy = 0; sy < 3; sy++) {
            int yn = y + 1 - sy;
            if (yn & 1) continue;
            int iy = yn >> 1;
            if ((unsigned)iy >= 14u) continue;
            for (int sx = 0; sx < 3; sx++) {
                int xn = xx + 1 - sx;
                if (xn & 1) continue;
                int ix = xn >> 1;
                if ((unsigned)ix >= 14u) continue;
                for (int ci = 0; ci < 8; ci++)
                    a += w3s[ci * 9 + sy * 3 + sx] * hd2s[ci * 196 + iy * 14 + ix];
            }
        }
        og[o] = 1.f / (1.f + expf(-a));
    }
}

extern "C" void kernel_launch(void* const* d_in, const int* in_sizes, int n_in,
                              void* d_out, int out_size, void* d_ws, size_t ws_size,
                              hipStream_t stream) {
    const float* x    = (const float*)d_in[0];
    const float* w1   = (const float*)d_in[1];
    const float* b1   = (const float*)d_in[2];
    const float* w2   = (const float*)d_in[3];
    const float* b2   = (const float*)d_in[4];
    const float* g2   = (const float*)d_in[5];
    const float* bt2  = (const float*)d_in[6];
    const float* w3   = (const float*)d_in[7];
    const float* b3   = (const float*)d_in[8];
    const float* proto= (const float*)d_in[9];
    const float* wup  = (const float*)d_in[10];
    const float* bup  = (const float*)d_in[11];
    const float* gup  = (const float*)d_in[12];
    const float* btup = (const float*)d_in[13];
    const float* wd1  = (const float*)d_in[14];
    const float* bd1  = (const float*)d_in[15];
    const float* gd1  = (const float*)d_in[16];
    const float* btd1 = (const float*)d_in[17];
    const float* wd2  = (const float*)d_in[18];
    const float* bd2  = (const float*)d_in[19];
    const float* gd2  = (const float*)d_in[20];
    const float* btd2 = (const float*)d_in[21];
    const float* wd3  = (const float*)d_in[22];
    const float* bd3  = (const float*)d_in[23];

    float* out0   = (float*)d_out;                 // [4096][784]
    float* out_md = out0 + (size_t)NB * 784;       // [4096][512]

    float* protoT = (float*)d_ws;                  // 256*512
    float* p2     = protoT + DC * PC;              // 512
    float* zg     = p2 + PC;                       // 4096*256
    float* zup    = zg + (size_t)NB * DC;          // 4096*6400

    hipLaunchKernelGGL(k_prep, dim3(PC), dim3(256), 0, stream, proto, protoT, p2);
    hipLaunchKernelGGL(k_enc_proto, dim3(NB), dim3(512), 0, stream,
                       x, w1, b1, w2, b2, g2, bt2, w3, b3,
                       proto, protoT, p2, out_md, zg);
    hipLaunchKernelGGL(k_zup, dim3(100, 64), dim3(256), 0, stream,
                       zg, wup, bup, gup, btup, zup);
    hipLaunchKernelGGL(k_dec, dim3(NB), dim3(256), 0, stream,
                       zup, wd1, bd1, gd1, btd1, wd2, bd2, gd2, btd2, wd3, bd3, out0);
}

// Round 2
// 1179.487 us; speedup vs baseline: 1.5204x; 1.5204x over previous
//
#include <hip/hip_runtime.h>
#include <hip/hip_bf16.h>
#include <math.h>

#define NB 4096
#define DC 256
#define PC 512

typedef unsigned short ushort_t;
typedef __attribute__((ext_vector_type(8))) unsigned short us8;

__device__ __forceinline__ float bf16_to_f(ushort_t u) {
    union { unsigned int i; float f; } c;
    c.i = ((unsigned int)u) << 16;
    return c.f;
}

// ---------------- K0: transpose protolayer + p2 ----------------
__global__ __launch_bounds__(256) void k_prep(const float* __restrict__ proto,
                                              float* __restrict__ protoT,
                                              float* __restrict__ p2) {
    int p = blockIdx.x;       // 0..511
    int d = threadIdx.x;      // 0..255
    float v = proto[p * DC + d];
    protoT[d * PC + p] = v;
    __shared__ float red[256];
    red[d] = v * v;
    __syncthreads();
    for (int s = 128; s > 0; s >>= 1) {
        if (d < s) red[d] += red[d + s];
        __syncthreads();
    }
    if (d == 0) p2[p] = red[0];
}

// ---------------- K0b: transpose wup -> wupT[d][pos*256+ch] ----------------
__global__ __launch_bounds__(256) void k_wt(const float* __restrict__ wup,
                                            float* __restrict__ wupT) {
    int d = blockIdx.x;       // 0..255
    for (int j = threadIdx.x; j < 6400; j += 256) {
        int ch = j & 255, pos = j >> 8;
        wupT[d * 6400 + j] = wup[d * 6400 + ch * 25 + pos];
    }
}

// ---------------- K1: encoder convs + prototype distances + softmax + z ----------------
__global__ __launch_bounds__(512) void k_enc_proto(
    const float* __restrict__ x,
    const float* __restrict__ w1, const float* __restrict__ b1,
    const float* __restrict__ w2, const float* __restrict__ b2,
    const float* __restrict__ g2, const float* __restrict__ bt2,
    const float* __restrict__ w3, const float* __restrict__ b3,
    const float* __restrict__ proto, const float* __restrict__ protoT,
    const float* __restrict__ p2,
    float* __restrict__ md_out,    // [B][512]
    float* __restrict__ zg)        // [B][256]
{
    int b = blockIdx.x;
    int t = threadIdx.x;

    __shared__ float xb[784];        // 28x28
    __shared__ float h1[8 * 196];    // 8x14x14
    __shared__ float h2[16 * 49];    // 16x7x7
    __shared__ float h3[256 * 28];   // 256 x 25 (padded to 28)
    __shared__ float x2s[25];
    __shared__ float red[512];
    __shared__ float wbuf[512];

    const float bnr = rsqrtf(1.0f + 1e-5f);

    const float* xg = x + b * 784;
    for (int i = t; i < 784; i += 512) xb[i] = xg[i];
    __syncthreads();

    // conv1: 1->8, k3 s2 p1, 28->14, bias+relu
    for (int o = t; o < 8 * 196; o += 512) {
        int c = o / 196, r = o % 196, y = r / 14, xx = r % 14;
        float acc = b1[c];
        for (int sy = 0; sy < 3; sy++) {
            int iy = 2 * y - 1 + sy;
            if ((unsigned)iy >= 28u) continue;
            for (int sx = 0; sx < 3; sx++) {
                int ix = 2 * xx - 1 + sx;
                if ((unsigned)ix >= 28u) continue;
                acc += w1[c * 9 + sy * 3 + sx] * xb[iy * 28 + ix];
            }
        }
        h1[o] = fmaxf(acc, 0.f);
    }
    __syncthreads();

    // conv2: 8->16, k3 s2 p1, 14->7, bias+bn+relu
    for (int o = t; o < 16 * 49; o += 512) {
        int c = o / 49, r = o % 49, y = r / 7, xx = r % 7;
        float acc = b2[c];
        for (int ci = 0; ci < 8; ci++) {
            for (int sy = 0; sy < 3; sy++) {
                int iy = 2 * y - 1 + sy;
                if ((unsigned)iy >= 14u) continue;
                for (int sx = 0; sx < 3; sx++) {
                    int ix = 2 * xx - 1 + sx;
                    if ((unsigned)ix >= 14u) continue;
                    acc += w2[((c * 8 + ci) * 3 + sy) * 3 + sx] * h1[ci * 196 + iy * 14 + ix];
                }
            }
        }
        float s = g2[c] * bnr;
        h2[o] = fmaxf(acc * s + bt2[c], 0.f);
    }
    __syncthreads();

    // conv3: 16->256, k3 s1 p0, 7->5, bias+relu. 512 threads: (d = t&255, half = t>>8) split ci.
    {
        int d = t & 255, half = t >> 8;
        float acc[25];
#pragma unroll
        for (int i = 0; i < 25; i++) acc[i] = 0.f;
        for (int ci = half * 8; ci < half * 8 + 8; ci++) {
            for (int s = 0; s < 9; s++) {
                int sy = s / 3, sx = s % 3;
                float w = w3[(d * 16 + ci) * 9 + s];
#pragma unroll
                for (int pos = 0; pos < 25; pos++) {
                    int y = pos / 5, xx = pos % 5;
                    acc[pos] += w * h2[ci * 49 + (y + sy) * 7 + (xx + sx)];
                }
            }
        }
        if (half == 1) {
#pragma unroll
            for (int pos = 0; pos < 25; pos++) h3[d * 28 + pos] = acc[pos];
        }
        __syncthreads();
        if (half == 0) {
            float bb = b3[d];
#pragma unroll
            for (int pos = 0; pos < 25; pos++) {
                float v = acc[pos] + h3[d * 28 + pos] + bb;
                h3[d * 28 + pos] = fmaxf(v, 0.f);
            }
        }
        __syncthreads();
    }

    // x2_patch_sum
    if (t < 25) {
        float s = 0.f;
        for (int d = 0; d < 256; d++) {
            float v = h3[d * 28 + t];
            s += v * v;
        }
        x2s[t] = s;
    }
    __syncthreads();

    // distances for prototype p = t; min over 25 positions (LDS reads vectorized)
    float mind;
    {
        int p = t;
        float acc[25];
#pragma unroll
        for (int i = 0; i < 25; i++) acc[i] = 0.f;
        for (int d = 0; d < 256; d++) {
            float pv = protoT[d * PC + p];
            const float4* hr = (const float4*)&h3[d * 28];
            float4 q0 = hr[0], q1 = hr[1], q2 = hr[2], q3 = hr[3], q4 = hr[4], q5 = hr[5];
            float lastv = h3[d * 28 + 24];
            acc[0] += pv * q0.x;  acc[1] += pv * q0.y;  acc[2] += pv * q0.z;  acc[3] += pv * q0.w;
            acc[4] += pv * q1.x;  acc[5] += pv * q1.y;  acc[6] += pv * q1.z;  acc[7] += pv * q1.w;
            acc[8] += pv * q2.x;  acc[9] += pv * q2.y;  acc[10] += pv * q2.z; acc[11] += pv * q2.w;
            acc[12] += pv * q3.x; acc[13] += pv * q3.y; acc[14] += pv * q3.z; acc[15] += pv * q3.w;
            acc[16] += pv * q4.x; acc[17] += pv * q4.y; acc[18] += pv * q4.z; acc[19] += pv * q4.w;
            acc[20] += pv * q5.x; acc[21] += pv * q5.y; acc[22] += pv * q5.z; acc[23] += pv * q5.w;
            acc[24] += pv * lastv;
        }
        float p2v = p2[p];
        mind = 1e30f;
#pragma unroll
        for (int pos = 0; pos < 25; pos++) {
            float dd = x2s[pos] - 2.f * acc[pos] + p2v;
            dd = fmaxf(dd, 0.f);
            mind = fminf(mind, dd);
        }
        md_out[b * PC + p] = mind;
    }

    // softmax over p of (-mind)
    float a = -mind;
    red[t] = a;
    __syncthreads();
    for (int s = 256; s > 0; s >>= 1) {
        if (t < s) red[t] = fmaxf(red[t], red[t + s]);
        __syncthreads();
    }
    float m = red[0];
    __syncthreads();
    float e = expf(a - m);
    red[t] = e;
    __syncthreads();
    for (int s = 256; s > 0; s >>= 1) {
        if (t < s) red[t] += red[t + s];
        __syncthreads();
    }
    float sum = red[0];
    wbuf[t] = e / sum;
    __syncthreads();

    // z[d] = sum_p w[p] * proto[p][d]
    if (t < 256) {
        float acc = 0.f;
        for (int p = 0; p < 512; p++) acc += wbuf[p] * proto[p * DC + t];
        zg[b * DC + t] = acc;
    }
}

// ---------------- K2: zup GEMM -> zupT (bf16, [b][pos][ch] layout), bias+bn+relu ----------------
__global__ __launch_bounds__(256) void k_zup(
    const float* __restrict__ zg, const float* __restrict__ wupT,
    const float* __restrict__ bup, const float* __restrict__ gup,
    const float* __restrict__ btup,
    __hip_bfloat16* __restrict__ zupT)
{
    __shared__ float As[32 * 65];   // [k][m] padded
    __shared__ float Bs[32 * 64];   // [k][n]
    int t = threadIdx.x;
    int n0 = blockIdx.x * 64;       // 100 blocks over n' = pos*256+ch
    int m0 = blockIdx.y * 64;       // 64 blocks
    int tx = t % 16, ty = t / 16;
    float acc[4][4];
#pragma unroll
    for (int i = 0; i < 4; i++)
#pragma unroll
        for (int j = 0; j < 4; j++) acc[i][j] = 0.f;

    for (int k0 = 0; k0 < 256; k0 += 32) {
        for (int i = t; i < 2048; i += 256) {
            int m = i / 32, k = i % 32;
            As[k * 65 + m] = zg[(m0 + m) * 256 + k0 + k];
        }
        for (int i = t; i < 2048; i += 256) {
            int k = i / 64, n = i % 64;
            Bs[k * 64 + n] = wupT[(k0 + k) * 6400 + n0 + n];
        }
        __syncthreads();
#pragma unroll 8
        for (int k = 0; k < 32; k++) {
            float a0 = As[k * 65 + ty], a1 = As[k * 65 + ty + 16];
            float a2 = As[k * 65 + ty + 32], a3 = As[k * 65 + ty + 48];
            float b0 = Bs[k * 64 + tx], b1 = Bs[k * 64 + tx + 16];
            float b2 = Bs[k * 64 + tx + 32], b3 = Bs[k * 64 + tx + 48];
            acc[0][0] += a0 * b0; acc[0][1] += a0 * b1; acc[0][2] += a0 * b2; acc[0][3] += a0 * b3;
            acc[1][0] += a1 * b0; acc[1][1] += a1 * b1; acc[1][2] += a1 * b2; acc[1][3] += a1 * b3;
            acc[2][0] += a2 * b0; acc[2][1] += a2 * b1; acc[2][2] += a2 * b2; acc[2][3] += a2 * b3;
            acc[3][0] += a3 * b0; acc[3][1] += a3 * b1; acc[3][2] += a3 * b2; acc[3][3] += a3 * b3;
        }
        __syncthreads();
    }

    const float bnr = rsqrtf(1.0f + 1e-5f);
#pragma unroll
    for (int i = 0; i < 4; i++) {
#pragma unroll
        for (int j = 0; j < 4; j++) {
            int m = m0 + ty + 16 * i, n = n0 + tx + 16 * j;
            int ch = n & 255;
            float s = gup[ch] * bnr;
            float v = (acc[i][j] + bup[ch]) * s + btup[ch];
            zupT[(size_t)m * 6400 + n] = __float2bfloat16(fmaxf(v, 0.f));
        }
    }
}

// ---------------- K3: wd1 as GEMM  P[102400][144] = zupT[102400][256] * wd1[256][144] ----------------
#define DG_BM 128
#define DG_BN 48
#define DG_BK 32
__global__ __launch_bounds__(256) void k_dgemm(
    const __hip_bfloat16* __restrict__ zupT,
    const float* __restrict__ wd1,
    float* __restrict__ P)
{
    __shared__ float As[DG_BK][DG_BM + 2];   // [k][m], 130 stride
    __shared__ float Bs[DG_BK][DG_BN];
    int t = threadIdx.x;
    int m0 = blockIdx.x * DG_BM;             // 800 blocks
    int n0 = blockIdx.y * DG_BN;             // 3 blocks
    int tx = t % 16, ty = t / 16;
    float acc[8][3];
#pragma unroll
    for (int i = 0; i < 8; i++)
#pragma unroll
        for (int j = 0; j < 3; j++) acc[i][j] = 0.f;

    for (int k0 = 0; k0 < 256; k0 += DG_BK) {
        // A: 128 rows x 32 k, bf16, 16B per thread-load
        for (int v = t; v < 512; v += 256) {
            int m = v >> 2;
            int kk = (v & 3) * 8;
            us8 u = *(const us8*)((const ushort_t*)zupT + (size_t)(m0 + m) * 256 + k0 + kk);
#pragma unroll
            for (int j = 0; j < 8; j++) As[kk + j][m] = bf16_to_f(u[j]);
        }
        // B: 32 x 48 fp32
        for (int v = t; v < DG_BK * DG_BN; v += 256) {
            int kk = v / DG_BN, n = v % DG_BN;
            Bs[kk][n] = wd1[(k0 + kk) * 144 + n0 + n];
        }
        __syncthreads();
#pragma unroll 4
        for (int k = 0; k < DG_BK; k++) {
            float2 p0 = *(const float2*)&As[k][2 * ty];
            float2 p1 = *(const float2*)&As[k][2 * ty + 32];
            float2 p2_ = *(const float2*)&As[k][2 * ty + 64];
            float2 p3 = *(const float2*)&As[k][2 * ty + 96];
            float b0 = Bs[k][tx], b1 = Bs[k][tx + 16], b2 = Bs[k][tx + 32];
            acc[0][0] += p0.x * b0; acc[0][1] += p0.x * b1; acc[0][2] += p0.x * b2;
            acc[1][0] += p0.y * b0; acc[1][1] += p0.y * b1; acc[1][2] += p0.y * b2;
            acc[2][0] += p1.x * b0; acc[2][1] += p1.x * b1; acc[2][2] += p1.x * b2;
            acc[3][0] += p1.y * b0; acc[3][1] += p1.y * b1; acc[3][2] += p1.y * b2;
            acc[4][0] += p2_.x * b0; acc[4][1] += p2_.x * b1; acc[4][2] += p2_.x * b2;
            acc[5][0] += p2_.y * b0; acc[5][1] += p2_.y * b1; acc[5][2] += p2_.y * b2;
            acc[6][0] += p3.x * b0; acc[6][1] += p3.x * b1; acc[6][2] += p3.x * b2;
            acc[7][0] += p3.y * b0; acc[7][1] += p3.y * b1; acc[7][2] += p3.y * b2;
        }
        __syncthreads();
    }

#pragma unroll
    for (int i = 0; i < 4; i++) {
#pragma unroll
        for (int j2 = 0; j2 < 2; j2++) {
            int m = m0 + 2 * ty + 32 * i + j2;
            float* pr = P + (size_t)m * 144 + n0;
            pr[tx]      = acc[2 * i + j2][0];
            pr[tx + 16] = acc[2 * i + j2][1];
            pr[tx + 32] = acc[2 * i + j2][2];
        }
    }
}

// ---------------- K4: gather wd1 + wd2 + wd3 + sigmoid, one block per image ----------------
__global__ __launch_bounds__(256) void k_dtail(
    const float* __restrict__ P,
    const float* __restrict__ bd1, const float* __restrict__ gd1, const float* __restrict__ btd1,
    const float* __restrict__ wd2, const float* __restrict__ bd2,
    const float* __restrict__ gd2, const float* __restrict__ btd2,
    const float* __restrict__ wd3, const float* __restrict__ bd3,
    float* __restrict__ out0)
{
    int b = blockIdx.x, t = threadIdx.x;
    __shared__ float Ps[25][148];
    __shared__ float hd1s[16 * 49];
    __shared__ float hd2s[8 * 196];
    __shared__ float w2s[1152];
    __shared__ float w3s[72];

    const float bnr = rsqrtf(1.0f + 1e-5f);

    const float* Pg = P + (size_t)b * 3600;
    for (int i = t; i < 3600; i += 256) Ps[i / 144][i % 144] = Pg[i];
    for (int i = t; i < 1152; i += 256) w2s[i] = wd2[i];
    if (t < 72) w3s[t] = wd3[t];
    __syncthreads();

    // wd1 gather + bias + bn + relu
    for (int o = t; o < 784; o += 256) {
        int co = o / 49, rr = o % 49, y = rr / 7, xx = rr % 7;
        float a = bd1[co];
        int sy0 = y - 4 > 0 ? y - 4 : 0, sy1 = y < 2 ? y : 2;
        for (int sy = sy0; sy <= sy1; sy++) {
            int iy = y - sy;
            int sx0 = xx - 4 > 0 ? xx - 4 : 0, sx1 = xx < 2 ? xx : 2;
            for (int sx = sx0; sx <= sx1; sx++) {
                int ix = xx - sx;
                a += Ps[iy * 5 + ix][co * 9 + sy * 3 + sx];
            }
        }
        float v = a * (gd1[co] * bnr) + btd1[co];
        hd1s[o] = fmaxf(v, 0.f);
    }
    __syncthreads();

    // wd2: convT 16->8, k3 s2 p1 op1, 7->14
    for (int o = t; o < 8 * 196; o += 256) {
        int co = o / 196, r = o % 196, y = r / 14, xx = r % 14;
        float a = 0.f;
        for (int sy = 0; sy < 3; sy++) {
            int yn = y + 1 - sy;
            if (yn & 1) continue;
            int iy = yn >> 1;
            if ((unsigned)iy >= 7u) continue;
            for (int sx = 0; sx < 3; sx++) {
                int xn = xx + 1 - sx;
                if (xn & 1) continue;
                int ix = xn >> 1;
                if ((unsigned)ix >= 7u) continue;
                for (int ci = 0; ci < 16; ci++)
                    a += w2s[(ci * 8 + co) * 9 + sy * 3 + sx] * hd1s[ci * 49 + iy * 7 + ix];
            }
        }
        float v = (a + bd2[co]) * (gd2[co] * bnr) + btd2[co];
        hd2s[o] = fmaxf(v, 0.f);
    }
    __syncthreads();

    // wd3: convT 8->1, k3 s2 p1 op1, 14->28, bias + sigmoid
    float* og = out0 + b * 784;
    for (int o = t; o < 784; o += 256) {
        int y = o / 28, xx = o % 28;
        float a = bd3[0];
        for (int sy = 0; sy < 3; sy++) {
            int yn = y + 1 - sy;
            if (yn & 1) continue;
            int iy = yn >> 1;
            if ((unsigned)iy >= 14u) continue;
            for (int sx = 0; sx < 3; sx++) {
                int xn = xx + 1 - sx;
                if (xn & 1) continue;
                int ix = xn >> 1;
                if ((unsigned)ix >= 14u) continue;
                for (int ci = 0; ci < 8; ci++)
                    a += w3s[ci * 9 + sy * 3 + sx] * hd2s[ci * 196 + iy * 14 + ix];
            }
        }
        og[o] = 1.f / (1.f + expf(-a));
    }
}

extern "C" void kernel_launch(void* const* d_in, const int* in_sizes, int n_in,
                              void* d_out, int out_size, void* d_ws, size_t ws_size,
                              hipStream_t stream) {
    const float* x    = (const float*)d_in[0];
    const float* w1   = (const float*)d_in[1];
    const float* b1   = (const float*)d_in[2];
    const float* w2   = (const float*)d_in[3];
    const float* b2   = (const float*)d_in[4];
    const float* g2   = (const float*)d_in[5];
    const float* bt2  = (const float*)d_in[6];
    const float* w3   = (const float*)d_in[7];
    const float* b3   = (const float*)d_in[8];
    const float* proto= (const float*)d_in[9];
    const float* wup  = (const float*)d_in[10];
    const float* bup  = (const float*)d_in[11];
    const float* gup  = (const float*)d_in[12];
    const float* btup = (const float*)d_in[13];
    const float* wd1  = (const float*)d_in[14];
    const float* bd1  = (const float*)d_in[15];
    const float* gd1  = (const float*)d_in[16];
    const float* btd1 = (const float*)d_in[17];
    const float* wd2  = (const float*)d_in[18];
    const float* bd2  = (const float*)d_in[19];
    const float* gd2  = (const float*)d_in[20];
    const float* btd2 = (const float*)d_in[21];
    const float* wd3  = (const float*)d_in[22];
    const float* bd3  = (const float*)d_in[23];

    float* out0   = (float*)d_out;                 // [4096][784]
    float* out_md = out0 + (size_t)NB * 784;       // [4096][512]

    // ws layout
    float* protoT = (float*)d_ws;                          // 256*512
    float* p2     = protoT + DC * PC;                      // 512
    float* zg     = p2 + PC;                               // 4096*256
    __hip_bfloat16* zupT = (__hip_bfloat16*)(zg + (size_t)NB * DC);   // 4096*6400 bf16
    float* wupT   = (float*)((char*)zupT + (size_t)NB * 6400 * sizeof(__hip_bfloat16)); // 256*6400
    float* P      = wupT;                                  // 102400*144 fp32 (overlaps wupT; wupT dead by then)

    hipLaunchKernelGGL(k_prep, dim3(PC), dim3(256), 0, stream, proto, protoT, p2);
    hipLaunchKernelGGL(k_wt, dim3(DC), dim3(256), 0, stream, wup, wupT);
    hipLaunchKernelGGL(k_enc_proto, dim3(NB), dim3(512), 0, stream,
                       x, w1, b1, w2, b2, g2, bt2, w3, b3,
                       proto, protoT, p2, out_md, zg);
    hipLaunchKernelGGL(k_zup, dim3(100, 64), dim3(256), 0, stream,
                       zg, wupT, bup, gup, btup, zupT);
    hipLaunchKernelGGL(k_dgemm, dim3(800, 3), dim3(256), 0, stream, zupT, wd1, P);
    hipLaunchKernelGGL(k_dtail, dim3(NB), dim3(256), 0, stream,
                       P, bd1, gd1, btd1, wd2, bd2, gd2, btd2, wd3, bd3, out0);
}

// Round 3
// 1078.988 us; speedup vs baseline: 1.6620x; 1.0931x over previous
//
#include <hip/hip_runtime.h>
#include <hip/hip_bf16.h>
#include <math.h>

#define NB 4096
#define DC 256
#define PC 512

typedef unsigned short ushort_t;
typedef __attribute__((ext_vector_type(8))) unsigned short us8;
typedef __attribute__((ext_vector_type(8))) short s8v;       // bf16x8 for MFMA
typedef __attribute__((ext_vector_type(4))) float f32x4;

__device__ __forceinline__ float bf16_to_f(ushort_t u) {
    union { unsigned int i; float f; } c;
    c.i = ((unsigned int)u) << 16;
    return c.f;
}
__device__ __forceinline__ ushort_t f2bf(float f) {          // RNE
    union { float f; unsigned int u; } c; c.f = f;
    unsigned int r = c.u + 0x7fffu + ((c.u >> 16) & 1u);
    return (ushort_t)(r >> 16);
}

// ---------------- K0: p2 ----------------
__global__ __launch_bounds__(256) void k_prep(const float* __restrict__ proto,
                                              float* __restrict__ p2) {
    int p = blockIdx.x;       // 0..511
    int d = threadIdx.x;      // 0..255
    float v = proto[p * DC + d];
    __shared__ float red[256];
    red[d] = v * v;
    __syncthreads();
    for (int s = 128; s > 0; s >>= 1) {
        if (d < s) red[d] += red[d + s];
        __syncthreads();
    }
    if (d == 0) p2[p] = red[0];
}

// ---------------- K0a: pack proto into MFMA B-fragment layout, bf16 hi/lo ----------------
// layout: frag[((nt*8 + k0)*64 + lane)*8 + j], n = nt*16 + (lane&15), k = k0*32 + (lane>>4)*8 + j
__global__ __launch_bounds__(256) void k_pack(const float* __restrict__ proto,
                                              ushort_t* __restrict__ pfragHi,
                                              ushort_t* __restrict__ pfragLo) {
    int idx = blockIdx.x * 256 + threadIdx.x;   // 512 blocks -> 131072
    int j  = idx & 7;
    int l  = (idx >> 3) & 63;
    int k0 = (idx >> 9) & 7;
    int nt = idx >> 12;
    int n = nt * 16 + (l & 15);
    int k = k0 * 32 + (l >> 4) * 8 + j;
    float v = proto[n * DC + k];
    ushort_t hi = f2bf(v);
    pfragHi[idx] = hi;
    pfragLo[idx] = f2bf(v - bf16_to_f(hi));
}

// ---------------- K0b: transpose wup -> wupT[d][pos*256+ch] ----------------
__global__ __launch_bounds__(256) void k_wt(const float* __restrict__ wup,
                                            float* __restrict__ wupT) {
    int d = blockIdx.x;       // 0..255
    for (int j = threadIdx.x; j < 6400; j += 256) {
        int ch = j & 255, pos = j >> 8;
        wupT[d * 6400 + j] = wup[d * 6400 + ch * 25 + pos];
    }
}

// ---------------- K0c: transpose w3 -> w3T[k][d], k = ci*9+s ----------------
__global__ __launch_bounds__(256) void k_w3t(const float* __restrict__ w3,
                                             float* __restrict__ w3T) {
    int k = blockIdx.x;       // 0..143
    int d = threadIdx.x;      // 0..255
    w3T[k * 256 + d] = w3[d * 144 + k];
}

// ---------------- K1: encoder convs + MFMA prototype distances + softmax + z ----------------
__global__ __launch_bounds__(512) void k_enc_proto(
    const float* __restrict__ x,
    const float* __restrict__ w1, const float* __restrict__ b1,
    const float* __restrict__ w2, const float* __restrict__ b2,
    const float* __restrict__ g2, const float* __restrict__ bt2,
    const float* __restrict__ w3T, const float* __restrict__ b3,
    const float* __restrict__ proto,
    const ushort_t* __restrict__ pfragHi, const ushort_t* __restrict__ pfragLo,
    const float* __restrict__ p2,
    float* __restrict__ md_out,    // [B][512]
    float* __restrict__ zg)        // [B][256]
{
    int b = blockIdx.x;
    int t = threadIdx.x;

    __shared__ float xb[784];
    __shared__ float h1[8 * 196];
    __shared__ float h2[16 * 49];
    __shared__ __align__(16) ushort_t h3hi[32 * 264];   // [pos][d], pad 264
    __shared__ __align__(16) ushort_t h3lo[32 * 264];
    __shared__ float x2s[32];
    __shared__ float x2part[32][8];
    __shared__ float red[512];
    __shared__ float wbuf[512];
    __shared__ float mds[512];

    const float bnr = rsqrtf(1.0f + 1e-5f);

    const float* xg = x + b * 784;
    for (int i = t; i < 784; i += 512) xb[i] = xg[i];
    __syncthreads();

    // conv1: 1->8, k3 s2 p1, 28->14, bias+relu
    for (int o = t; o < 8 * 196; o += 512) {
        int c = o / 196, r = o % 196, y = r / 14, xx = r % 14;
        float acc = b1[c];
        for (int sy = 0; sy < 3; sy++) {
            int iy = 2 * y - 1 + sy;
            if ((unsigned)iy >= 28u) continue;
            for (int sx = 0; sx < 3; sx++) {
                int ix = 2 * xx - 1 + sx;
                if ((unsigned)ix >= 28u) continue;
                acc += w1[c * 9 + sy * 3 + sx] * xb[iy * 28 + ix];
            }
        }
        h1[o] = fmaxf(acc, 0.f);
    }
    __syncthreads();

    // conv2: 8->16, k3 s2 p1, 14->7, bias+bn+relu
    for (int o = t; o < 16 * 49; o += 512) {
        int c = o / 49, r = o % 49, y = r / 7, xx = r % 7;
        float acc = b2[c];
        for (int ci = 0; ci < 8; ci++) {
            for (int sy = 0; sy < 3; sy++) {
                int iy = 2 * y - 1 + sy;
                if ((unsigned)iy >= 14u) continue;
                for (int sx = 0; sx < 3; sx++) {
                    int ix = 2 * xx - 1 + sx;
                    if ((unsigned)ix >= 14u) continue;
                    acc += w2[((c * 8 + ci) * 3 + sy) * 3 + sx] * h1[ci * 196 + iy * 14 + ix];
                }
            }
        }
        float s = g2[c] * bnr;
        h2[o] = fmaxf(acc * s + bt2[c], 0.f);
    }
    __syncthreads();

    // conv3: 16->256, k3 s1 p0, 7->5, bias+relu; 4 waves (t<256), d = t.
    // writes h3T[pos][d] as bf16 hi/lo
    if (t < 256) {
        int d = t;
        float acc[25];
#pragma unroll
        for (int i = 0; i < 25; i++) acc[i] = 0.f;
        for (int ci = 0; ci < 16; ci++) {
            const float* h2p = &h2[ci * 49];
#pragma unroll
            for (int s = 0; s < 9; s++) {
                int sy = s / 3, sx = s % 3;
                float w = w3T[(ci * 9 + s) * 256 + d];
#pragma unroll
                for (int pos = 0; pos < 25; pos++) {
                    acc[pos] += w * h2p[(pos / 5 + sy) * 7 + (pos % 5 + sx)];
                }
            }
        }
        float bb = b3[d];
#pragma unroll
        for (int pos = 0; pos < 25; pos++) {
            float h = fmaxf(acc[pos] + bb, 0.f);
            ushort_t hi = f2bf(h);
            h3hi[pos * 264 + d] = hi;
            h3lo[pos * 264 + d] = f2bf(h - bf16_to_f(hi));
        }
    }
    // zero pad rows 25..31
    for (int i = t; i < 7 * 264; i += 512) {
        h3hi[25 * 264 + i] = 0;
        h3lo[25 * 264 + i] = 0;
    }
    __syncthreads();

    // x2_patch_sum partials: t<256: pos = t>>3, chunk = t&7 (32 d's each)
    if (t < 256) {
        int pos = t >> 3, ch = t & 7;
        const ushort_t* ph = &h3hi[pos * 264 + ch * 32];
        const ushort_t* pl = &h3lo[pos * 264 + ch * 32];
        float s = 0.f;
#pragma unroll
        for (int i = 0; i < 32; i += 8) {
            us8 vh = *(const us8*)(ph + i);
            us8 vl = *(const us8*)(pl + i);
#pragma unroll
            for (int j = 0; j < 8; j++) {
                float f = bf16_to_f(vh[j]) + bf16_to_f(vl[j]);
                s = fmaf(f, f, s);
            }
        }
        x2part[pos][ch] = s;
    }
    __syncthreads();
    if (t < 32) {
        float s = 1e30f;
        if (t < 25) {
            s = 0.f;
#pragma unroll
            for (int c = 0; c < 8; c++) s += x2part[t][c];
        }
        x2s[t] = s;
    }
    __syncthreads();

    // MFMA distances: xp[32 pos][512 p], wave w handles p-cols [w*64, w*64+64)
    {
        int w = t >> 6, l = t & 63, lr = l & 15, lg = l >> 4;
        f32x4 acc0[4], acc1[4];
#pragma unroll
        for (int i = 0; i < 4; i++) {
            acc0[i] = (f32x4){0.f, 0.f, 0.f, 0.f};
            acc1[i] = (f32x4){0.f, 0.f, 0.f, 0.f};
        }
        const s8v* BH = (const s8v*)pfragHi;
        const s8v* BL = (const s8v*)pfragLo;
        int ntb = w * 4;
#pragma unroll 2
        for (int k0 = 0; k0 < 8; k0++) {
            s8v ah0 = *(const s8v*)&h3hi[lr * 264 + k0 * 32 + lg * 8];
            s8v ah1 = *(const s8v*)&h3hi[(16 + lr) * 264 + k0 * 32 + lg * 8];
            s8v al0 = *(const s8v*)&h3lo[lr * 264 + k0 * 32 + lg * 8];
            s8v al1 = *(const s8v*)&h3lo[(16 + lr) * 264 + k0 * 32 + lg * 8];
#pragma unroll
            for (int n2 = 0; n2 < 4; n2++) {
                s8v bh = BH[((ntb + n2) * 8 + k0) * 64 + l];
                s8v bl = BL[((ntb + n2) * 8 + k0) * 64 + l];
                acc0[n2] = __builtin_amdgcn_mfma_f32_16x16x32_bf16(ah0, bh, acc0[n2], 0, 0, 0);
                acc1[n2] = __builtin_amdgcn_mfma_f32_16x16x32_bf16(ah1, bh, acc1[n2], 0, 0, 0);
                acc0[n2] = __builtin_amdgcn_mfma_f32_16x16x32_bf16(al0, bh, acc0[n2], 0, 0, 0);
                acc1[n2] = __builtin_amdgcn_mfma_f32_16x16x32_bf16(al1, bh, acc1[n2], 0, 0, 0);
                acc0[n2] = __builtin_amdgcn_mfma_f32_16x16x32_bf16(ah0, bl, acc0[n2], 0, 0, 0);
                acc1[n2] = __builtin_amdgcn_mfma_f32_16x16x32_bf16(ah1, bl, acc1[n2], 0, 0, 0);
            }
        }
        // epilogue: dd = relu(x2s[row] - 2*xp + p2[p]); min over rows
        float x2r[8];
#pragma unroll
        for (int r = 0; r < 4; r++) {
            x2r[r]     = x2s[lg * 4 + r];
            x2r[4 + r] = x2s[16 + lg * 4 + r];
        }
#pragma unroll
        for (int n2 = 0; n2 < 4; n2++) {
            int pcol = w * 64 + n2 * 16 + lr;
            float p2v = p2[pcol];
            float mm = 1e30f;
#pragma unroll
            for (int r = 0; r < 4; r++) {
                float d0 = fmaxf(x2r[r]     - 2.f * acc0[n2][r] + p2v, 0.f);
                float d1 = fmaxf(x2r[4 + r] - 2.f * acc1[n2][r] + p2v, 0.f);
                mm = fminf(mm, fminf(d0, d1));
            }
            mm = fminf(mm, __shfl_xor(mm, 16));
            mm = fminf(mm, __shfl_xor(mm, 32));
            if (lg == 0) mds[pcol] = mm;
        }
    }
    __syncthreads();

    // softmax over p of (-mind)
    float mind = mds[t];
    md_out[b * PC + t] = mind;
    float a = -mind;
    red[t] = a;
    __syncthreads();
    for (int s = 256; s > 0; s >>= 1) {
        if (t < s) red[t] = fmaxf(red[t], red[t + s]);
        __syncthreads();
    }
    float m = red[0];
    __syncthreads();
    float e = expf(a - m);
    red[t] = e;
    __syncthreads();
    for (int s = 256; s > 0; s >>= 1) {
        if (t < s) red[t] += red[t + s];
        __syncthreads();
    }
    float sum = red[0];
    wbuf[t] = e / sum;
    __syncthreads();

    // z[d] = sum_p w[p] * proto[p][d], split over 2 halves of p
    {
        int d = t & 255, ph = t >> 8;
        float accz = 0.f;
        for (int p = ph * 256; p < ph * 256 + 256; p++)
            accz += wbuf[p] * proto[p * DC + d];
        red[t] = accz;
    }
    __syncthreads();
    if (t < 256) zg[b * DC + t] = red[t] + red[t + 256];
}

// ---------------- K2: zup GEMM -> zupT (bf16, [b][pos][ch] layout), bias+bn+relu ----------------
__global__ __launch_bounds__(256) void k_zup(
    const float* __restrict__ zg, const float* __restrict__ wupT,
    const float* __restrict__ bup, const float* __restrict__ gup,
    const float* __restrict__ btup,
    __hip_bfloat16* __restrict__ zupT)
{
    __shared__ float As[32 * 65];
    __shared__ float Bs[32 * 64];
    int t = threadIdx.x;
    int n0 = blockIdx.x * 64;
    int m0 = blockIdx.y * 64;
    int tx = t % 16, ty = t / 16;
    float acc[4][4];
#pragma unroll
    for (int i = 0; i < 4; i++)
#pragma unroll
        for (int j = 0; j < 4; j++) acc[i][j] = 0.f;

    for (int k0 = 0; k0 < 256; k0 += 32) {
        for (int i = t; i < 2048; i += 256) {
            int m = i / 32, k = i % 32;
            As[k * 65 + m] = zg[(m0 + m) * 256 + k0 + k];
        }
        for (int i = t; i < 2048; i += 256) {
            int k = i / 64, n = i % 64;
            Bs[k * 64 + n] = wupT[(k0 + k) * 6400 + n0 + n];
        }
        __syncthreads();
#pragma unroll 8
        for (int k = 0; k < 32; k++) {
            float a0 = As[k * 65 + ty], a1 = As[k * 65 + ty + 16];
            float a2 = As[k * 65 + ty + 32], a3 = As[k * 65 + ty + 48];
            float b0 = Bs[k * 64 + tx], b1 = Bs[k * 64 + tx + 16];
            float b2 = Bs[k * 64 + tx + 32], b3 = Bs[k * 64 + tx + 48];
            acc[0][0] += a0 * b0; acc[0][1] += a0 * b1; acc[0][2] += a0 * b2; acc[0][3] += a0 * b3;
            acc[1][0] += a1 * b0; acc[1][1] += a1 * b1; acc[1][2] += a1 * b2; acc[1][3] += a1 * b3;
            acc[2][0] += a2 * b0; acc[2][1] += a2 * b1; acc[2][2] += a2 * b2; acc[2][3] += a2 * b3;
            acc[3][0] += a3 * b0; acc[3][1] += a3 * b1; acc[3][2] += a3 * b2; acc[3][3] += a3 * b3;
        }
        __syncthreads();
    }

    const float bnr = rsqrtf(1.0f + 1e-5f);
#pragma unroll
    for (int i = 0; i < 4; i++) {
#pragma unroll
        for (int j = 0; j < 4; j++) {
            int m = m0 + ty + 16 * i, n = n0 + tx + 16 * j;
            int ch = n & 255;
            float s = gup[ch] * bnr;
            float v = (acc[i][j] + bup[ch]) * s + btup[ch];
            zupT[(size_t)m * 6400 + n] = __float2bfloat16(fmaxf(v, 0.f));
        }
    }
}

// ---------------- K3: wd1 as GEMM  P[102400][144] = zupT[102400][256] * wd1[256][144] ----------------
#define DG_BM 128
#define DG_BN 48
#define DG_BK 32
__global__ __launch_bounds__(256) void k_dgemm(
    const __hip_bfloat16* __restrict__ zupT,
    const float* __restrict__ wd1,
    float* __restrict__ P)
{
    __shared__ float As[DG_BK][DG_BM + 2];
    __shared__ float Bs[DG_BK][DG_BN];
    int t = threadIdx.x;
    int m0 = blockIdx.x * DG_BM;
    int n0 = blockIdx.y * DG_BN;
    int tx = t % 16, ty = t / 16;
    float acc[8][3];
#pragma unroll
    for (int i = 0; i < 8; i++)
#pragma unroll
        for (int j = 0; j < 3; j++) acc[i][j] = 0.f;

    for (int k0 = 0; k0 < 256; k0 += DG_BK) {
        for (int v = t; v < 512; v += 256) {
            int m = v >> 2;
            int kk = (v & 3) * 8;
            us8 u = *(const us8*)((const ushort_t*)zupT + (size_t)(m0 + m) * 256 + k0 + kk);
#pragma unroll
            for (int j = 0; j < 8; j++) As[kk + j][m] = bf16_to_f(u[j]);
        }
        for (int v = t; v < DG_BK * DG_BN; v += 256) {
            int kk = v / DG_BN, n = v % DG_BN;
            Bs[kk][n] = wd1[(k0 + kk) * 144 + n0 + n];
        }
        __syncthreads();
#pragma unroll 4
        for (int k = 0; k < DG_BK; k++) {
            float2 p0 = *(const float2*)&As[k][2 * ty];
            float2 p1 = *(const float2*)&As[k][2 * ty + 32];
            float2 p2_ = *(const float2*)&As[k][2 * ty + 64];
            float2 p3 = *(const float2*)&As[k][2 * ty + 96];
            float b0 = Bs[k][tx], b1 = Bs[k][tx + 16], b2 = Bs[k][tx + 32];
            acc[0][0] += p0.x * b0; acc[0][1] += p0.x * b1; acc[0][2] += p0.x * b2;
            acc[1][0] += p0.y * b0; acc[1][1] += p0.y * b1; acc[1][2] += p0.y * b2;
            acc[2][0] += p1.x * b0; acc[2][1] += p1.x * b1; acc[2][2] += p1.x * b2;
            acc[3][0] += p1.y * b0; acc[3][1] += p1.y * b1; acc[3][2] += p1.y * b2;
            acc[4][0] += p2_.x * b0; acc[4][1] += p2_.x * b1; acc[4][2] += p2_.x * b2;
            acc[5][0] += p2_.y * b0; acc[5][1] += p2_.y * b1; acc[5][2] += p2_.y * b2;
            acc[6][0] += p3.x * b0; acc[6][1] += p3.x * b1; acc[6][2] += p3.x * b2;
            acc[7][0] += p3.y * b0; acc[7][1] += p3.y * b1; acc[7][2] += p3.y * b2;
        }
        __syncthreads();
    }

#pragma unroll
    for (int i = 0; i < 4; i++) {
#pragma unroll
        for (int j2 = 0; j2 < 2; j2++) {
            int m = m0 + 2 * ty + 32 * i + j2;
            float* pr = P + (size_t)m * 144 + n0;
            pr[tx]      = acc[2 * i + j2][0];
            pr[tx + 16] = acc[2 * i + j2][1];
            pr[tx + 32] = acc[2 * i + j2][2];
        }
    }
}

// ---------------- K4: gather wd1 + wd2 + wd3 + sigmoid, one block per image ----------------
__global__ __launch_bounds__(256) void k_dtail(
    const float* __restrict__ P,
    const float* __restrict__ bd1, const float* __restrict__ gd1, const float* __restrict__ btd1,
    const float* __restrict__ wd2, const float* __restrict__ bd2,
    const float* __restrict__ gd2, const float* __restrict__ btd2,
    const float* __restrict__ wd3, const float* __restrict__ bd3,
    float* __restrict__ out0)
{
    int b = blockIdx.x, t = threadIdx.x;
    __shared__ float Ps[25][148];
    __shared__ float hd1s[16 * 49];
    __shared__ float hd2s[8 * 196];
    __shared__ float w2s[1152];
    __shared__ float w3s[72];

    const float bnr = rsqrtf(1.0f + 1e-5f);

    const float* Pg = P + (size_t)b * 3600;
    for (int i = t; i < 3600; i += 256) Ps[i / 144][i % 144] = Pg[i];
    for (int i = t; i < 1152; i += 256) w2s[i] = wd2[i];
    if (t < 72) w3s[t] = wd3[t];
    __syncthreads();

    for (int o = t; o < 784; o += 256) {
        int co = o / 49, rr = o % 49, y = rr / 7, xx = rr % 7;
        float a = bd1[co];
        int sy0 = y - 4 > 0 ? y - 4 : 0, sy1 = y < 2 ? y : 2;
        for (int sy = sy0; sy <= sy1; sy++) {
            int iy = y - sy;
            int sx0 = xx - 4 > 0 ? xx - 4 : 0, sx1 = xx < 2 ? xx : 2;
            for (int sx = sx0; sx <= sx1; sx++) {
                int ix = xx - sx;
                a += Ps[iy * 5 + ix][co * 9 + sy * 3 + sx];
            }
        }
        float v = a * (gd1[co] * bnr) + btd1[co];
        hd1s[o] = fmaxf(v, 0.f);
    }
    __syncthreads();

    for (int o = t; o < 8 * 196; o += 256) {
        int co = o / 196, r = o % 196, y = r / 14, xx = r % 14;
        float a = 0.f;
        for (int sy = 0; sy < 3; sy++) {
            int yn = y + 1 - sy;
            if (yn & 1) continue;
            int iy = yn >> 1;
            if ((unsigned)iy >= 7u) continue;
            for (int sx = 0; sx < 3; sx++) {
                int xn = xx + 1 - sx;
                if (xn & 1) continue;
                int ix = xn >> 1;
                if ((unsigned)ix >= 7u) continue;
                for (int ci = 0; ci < 16; ci++)
                    a += w2s[(ci * 8 + co) * 9 + sy * 3 + sx] * hd1s[ci * 49 + iy * 7 + ix];
            }
        }
        float v = (a + bd2[co]) * (gd2[co] * bnr) + btd2[co];
        hd2s[o] = fmaxf(v, 0.f);
    }
    __syncthreads();

    float* og = out0 + b * 784;
    for (int o = t; o < 784; o += 256) {
        int y = o / 28, xx = o % 28;
        float a = bd3[0];
        for (int sy = 0; sy < 3; sy++) {
            int yn = y + 1 - sy;
            if (yn & 1) continue;
            int iy = yn >> 1;
            if ((unsigned)iy >= 14u) continue;
            for (int sx = 0; sx < 3; sx++) {
                int xn = xx + 1 - sx;
                if (xn & 1) continue;
                int ix = xn >> 1;
                if ((unsigned)ix >= 14u) continue;
                for (int ci = 0; ci < 8; ci++)
                    a += w3s[ci * 9 + sy * 3 + sx] * hd2s[ci * 196 + iy * 14 + ix];
            }
        }
        og[o] = 1.f / (1.f + expf(-a));
    }
}

extern "C" void kernel_launch(void* const* d_in, const int* in_sizes, int n_in,
                              void* d_out, int out_size, void* d_ws, size_t ws_size,
                              hipStream_t stream) {
    const float* x    = (const float*)d_in[0];
    const float* w1   = (const float*)d_in[1];
    const float* b1   = (const float*)d_in[2];
    const float* w2   = (const float*)d_in[3];
    const float* b2   = (const float*)d_in[4];
    const float* g2   = (const float*)d_in[5];
    const float* bt2  = (const float*)d_in[6];
    const float* w3   = (const float*)d_in[7];
    const float* b3   = (const float*)d_in[8];
    const float* proto= (const float*)d_in[9];
    const float* wup  = (const float*)d_in[10];
    const float* bup  = (const float*)d_in[11];
    const float* gup  = (const float*)d_in[12];
    const float* btup = (const float*)d_in[13];
    const float* wd1  = (const float*)d_in[14];
    const float* bd1  = (const float*)d_in[15];
    const float* gd1  = (const float*)d_in[16];
    const float* btd1 = (const float*)d_in[17];
    const float* wd2  = (const float*)d_in[18];
    const float* bd2  = (const float*)d_in[19];
    const float* gd2  = (const float*)d_in[20];
    const float* btd2 = (const float*)d_in[21];
    const float* wd3  = (const float*)d_in[22];
    const float* bd3  = (const float*)d_in[23];

    float* out0   = (float*)d_out;                 // [4096][784]
    float* out_md = out0 + (size_t)NB * 784;       // [4096][512]

    // ws layout
    float*    p2      = (float*)d_ws;                          // 512
    ushort_t* pfragHi = (ushort_t*)(p2 + PC);                  // 131072
    ushort_t* pfragLo = pfragHi + 131072;                      // 131072
    float*    w3T     = (float*)(pfragLo + 131072);            // 144*256
    float*    zg      = w3T + 144 * 256;                       // 4096*256
    __hip_bfloat16* zupT = (__hip_bfloat16*)(zg + (size_t)NB * DC);   // 4096*6400 bf16
    float*    wupT    = (float*)((char*)zupT + (size_t)NB * 6400 * sizeof(__hip_bfloat16)); // 256*6400
    float*    P       = wupT;                                  // 102400*144 fp32 (overlaps dead wupT)

    hipLaunchKernelGGL(k_prep, dim3(PC), dim3(256), 0, stream, proto, p2);
    hipLaunchKernelGGL(k_pack, dim3(512), dim3(256), 0, stream, proto, pfragHi, pfragLo);
    hipLaunchKernelGGL(k_wt, dim3(DC), dim3(256), 0, stream, wup, wupT);
    hipLaunchKernelGGL(k_w3t, dim3(144), dim3(256), 0, stream, w3, w3T);
    hipLaunchKernelGGL(k_enc_proto, dim3(NB), dim3(512), 0, stream,
                       x, w1, b1, w2, b2, g2, bt2, w3T, b3,
                       proto, pfragHi, pfragLo, p2, out_md, zg);
    hipLaunchKernelGGL(k_zup, dim3(100, 64), dim3(256), 0, stream,
                       zg, wupT, bup, gup, btup, zupT);
    hipLaunchKernelGGL(k_dgemm, dim3(800, 3), dim3(256), 0, stream, zupT, wd1, P);
    hipLaunchKernelGGL(k_dtail, dim3(NB), dim3(256), 0, stream,
                       P, bd1, gd1, btd1, wd2, bd2, gd2, btd2, wd3, bd3, out0);
}

// Round 4
// 648.548 us; speedup vs baseline: 2.7651x; 1.6637x over previous
//
#include <hip/hip_runtime.h>
#include <hip/hip_bf16.h>
#include <math.h>

#define NB 4096
#define DC 256
#define PC 512

typedef unsigned short ushort_t;
typedef __attribute__((ext_vector_type(8))) unsigned short us8;
typedef __attribute__((ext_vector_type(8))) short s8v;       // bf16x8 for MFMA
typedef __attribute__((ext_vector_type(4))) float f32x4;

__device__ __forceinline__ float bf16_to_f(ushort_t u) {
    union { unsigned int i; float f; } c;
    c.i = ((unsigned int)u) << 16;
    return c.f;
}
__device__ __forceinline__ ushort_t f2bf(float f) {          // RNE
    union { float f; unsigned int u; } c; c.f = f;
    unsigned int r = c.u + 0x7fffu + ((c.u >> 16) & 1u);
    return (ushort_t)(r >> 16);
}

// ---------------- K0: p2 ----------------
__global__ __launch_bounds__(256) void k_prep(const float* __restrict__ proto,
                                              float* __restrict__ p2) {
    int p = blockIdx.x;       // 0..511
    int d = threadIdx.x;      // 0..255
    float v = proto[p * DC + d];
    __shared__ float red[256];
    red[d] = v * v;
    __syncthreads();
    for (int s = 128; s > 0; s >>= 1) {
        if (d < s) red[d] += red[d + s];
        __syncthreads();
    }
    if (d == 0) p2[p] = red[0];
}

// ---------------- K0a: pack proto into MFMA B-fragment layout, bf16 hi/lo ----------------
// frag[((nt*8 + k0)*64 + lane)*8 + j], n = nt*16 + (lane&15), k = k0*32 + (lane>>4)*8 + j
__global__ __launch_bounds__(256) void k_pack(const float* __restrict__ proto,
                                              ushort_t* __restrict__ pfragHi,
                                              ushort_t* __restrict__ pfragLo) {
    int idx = blockIdx.x * 256 + threadIdx.x;   // 512 blocks -> 131072
    int j  = idx & 7;
    int l  = (idx >> 3) & 63;
    int k0 = (idx >> 9) & 7;
    int nt = idx >> 12;
    int n = nt * 16 + (l & 15);
    int k = k0 * 32 + (l >> 4) * 8 + j;
    float v = proto[n * DC + k];
    ushort_t hi = f2bf(v);
    pfragHi[idx] = hi;
    pfragLo[idx] = f2bf(v - bf16_to_f(hi));
}

// ---------------- K0c: transpose w3 -> w3T[k][d], k = ci*9+s ----------------
__global__ __launch_bounds__(256) void k_w3t(const float* __restrict__ w3,
                                             float* __restrict__ w3T) {
    int k = blockIdx.x;       // 0..143
    int d = threadIdx.x;      // 0..255
    w3T[k * 256 + d] = w3[d * 144 + k];
}

// ---------------- K0d: pack wd1 -> bf16 B-fragments [9 nt][8 k0][64][8] ----------------
__global__ __launch_bounds__(256) void k_wd1p(const float* __restrict__ wd1,
                                              ushort_t* __restrict__ wd1frag) {
    int idx = blockIdx.x * 256 + threadIdx.x;   // 144 blocks -> 36864
    int j  = idx & 7;
    int l  = (idx >> 3) & 63;
    int k0 = (idx >> 9) & 7;
    int nt = idx >> 12;                          // 0..8
    int n = nt * 16 + (l & 15);                  // 0..143
    int k = k0 * 32 + (l >> 4) * 8 + j;          // 0..255
    wd1frag[idx] = f2bf(wd1[k * 144 + n]);
}

// ---------------- K0e: PW = proto x wupT, stored as bf16 B-fragments for k_zup2 ----------
// PW[p][n'], n' = pos*256+ch ; frag: n=n', k=p : [400 nt][16 k0][64][8]
__global__ __launch_bounds__(256) void k_pw(
    const float* __restrict__ proto,   // [512][256]
    const float* __restrict__ wup,     // [256][6400] native cols = ch*25+pos
    ushort_t* __restrict__ PWfrag)
{
    __shared__ float As[32 * 65];
    __shared__ float Bs[32 * 64];
    int t = threadIdx.x;
    int n0 = blockIdx.x * 64;          // native col
    int m0 = blockIdx.y * 64;          // p
    int tx = t % 16, ty = t / 16;
    float acc[4][4];
#pragma unroll
    for (int i = 0; i < 4; i++)
#pragma unroll
        for (int j = 0; j < 4; j++) acc[i][j] = 0.f;

    for (int k0 = 0; k0 < 256; k0 += 32) {
        for (int i = t; i < 2048; i += 256) {
            int m = i / 32, k = i % 32;
            As[k * 65 + m] = proto[(m0 + m) * 256 + k0 + k];
        }
        for (int i = t; i < 2048; i += 256) {
            int k = i / 64, n = i % 64;
            Bs[k * 64 + n] = wup[(k0 + k) * 6400 + n0 + n];
        }
        __syncthreads();
#pragma unroll 8
        for (int k = 0; k < 32; k++) {
            float a0 = As[k * 65 + ty], a1 = As[k * 65 + ty + 16];
            float a2 = As[k * 65 + ty + 32], a3 = As[k * 65 + ty + 48];
            float b0 = Bs[k * 64 + tx], b1 = Bs[k * 64 + tx + 16];
            float b2 = Bs[k * 64 + tx + 32], b3 = Bs[k * 64 + tx + 48];
            acc[0][0] += a0 * b0; acc[0][1] += a0 * b1; acc[0][2] += a0 * b2; acc[0][3] += a0 * b3;
            acc[1][0] += a1 * b0; acc[1][1] += a1 * b1; acc[1][2] += a1 * b2; acc[1][3] += a1 * b3;
            acc[2][0] += a2 * b0; acc[2][1] += a2 * b1; acc[2][2] += a2 * b2; acc[2][3] += a2 * b3;
            acc[3][0] += a3 * b0; acc[3][1] += a3 * b1; acc[3][2] += a3 * b2; acc[3][3] += a3 * b3;
        }
        __syncthreads();
    }

#pragma unroll
    for (int i = 0; i < 4; i++) {
#pragma unroll
        for (int j = 0; j < 4; j++) {
            int p  = m0 + ty + 16 * i;
            int nn = n0 + tx + 16 * j;           // native
            int ch = nn / 25, pos = nn % 25;
            int np = pos * 256 + ch;             // n'
            int nt = np >> 4, k0p = p >> 5;
            int ll = ((p >> 3) & 3) * 16 + (np & 15);
            int jj = p & 7;
            PWfrag[(((nt * 16 + k0p) * 64) + ll) * 8 + jj] = f2bf(acc[i][j]);
        }
    }
}

// ---------------- conv3 helper: compile-time positions (even/odd split) ----------------
template<int HALF>
__device__ __forceinline__ void conv3_compute(const float* h2,
                                              const float* __restrict__ w3T,
                                              float bb, int d,
                                              ushort_t* h3hi, ushort_t* h3lo) {
    float acc[13];
#pragma unroll
    for (int pp = 0; pp < 13; pp++) acc[pp] = 0.f;
    for (int ci = 0; ci < 16; ci++) {
        float qv[52];
        const float* h2p = &h2[ci * 52];
#pragma unroll
        for (int qq = 0; qq < 13; qq++) {
            float4 tmp = *(const float4*)&h2p[qq * 4];
            qv[4 * qq]     = tmp.x; qv[4 * qq + 1] = tmp.y;
            qv[4 * qq + 2] = tmp.z; qv[4 * qq + 3] = tmp.w;
        }
#pragma unroll
        for (int s = 0; s < 9; s++) {
            const int sy = s / 3, sx = s % 3;
            float w = w3T[(ci * 9 + s) * 256 + d];
#pragma unroll
            for (int pp = 0; pp < 13; pp++) {
                const int pos = 2 * pp + HALF;
                if (pos < 25) {
                    const int tap = (pos / 5) * 7 + (pos % 5) + sy * 7 + sx;
                    acc[pp] += w * qv[tap];
                }
            }
        }
    }
#pragma unroll
    for (int pp = 0; pp < 13; pp++) {
        const int pos = 2 * pp + HALF;
        if (pos < 25) {
            float h = fmaxf(acc[pp] + bb, 0.f);
            ushort_t hi = f2bf(h);
            h3hi[pos * 264 + d] = hi;
            h3lo[pos * 264 + d] = f2bf(h - bf16_to_f(hi));
        }
    }
}

// ---------------- K1: encoder convs + MFMA prototype distances + softmax -> Wsm ----------
__global__ __launch_bounds__(512) void k_enc_proto(
    const float* __restrict__ x,
    const float* __restrict__ w1, const float* __restrict__ b1,
    const float* __restrict__ w2, const float* __restrict__ b2,
    const float* __restrict__ g2, const float* __restrict__ bt2,
    const float* __restrict__ w3T, const float* __restrict__ b3,
    const ushort_t* __restrict__ pfragHi, const ushort_t* __restrict__ pfragLo,
    const float* __restrict__ p2,
    float* __restrict__ md_out,    // [B][512]
    ushort_t* __restrict__ Wsm)    // [B][512] bf16 softmax weights
{
    int b = blockIdx.x;
    int t = threadIdx.x;

    __shared__ float xb[784];
    __shared__ float h1[8 * 196];
    __shared__ float h2[16 * 52];                       // stride 52 (16B-aligned rows)
    __shared__ __align__(16) ushort_t h3hi[32 * 264];   // [pos][d]
    __shared__ __align__(16) ushort_t h3lo[32 * 264];
    __shared__ float x2s[32];
    __shared__ float x2part[32][8];
    __shared__ float red[512];
    __shared__ float mds[512];

    const float bnr = rsqrtf(1.0f + 1e-5f);

    const float* xg = x + b * 784;
    for (int i = t; i < 784; i += 512) xb[i] = xg[i];
    __syncthreads();

    // conv1: 1->8, k3 s2 p1, 28->14, bias+relu
    for (int o = t; o < 8 * 196; o += 512) {
        int c = o / 196, r = o % 196, y = r / 14, xx = r % 14;
        float acc = b1[c];
        for (int sy = 0; sy < 3; sy++) {
            int iy = 2 * y - 1 + sy;
            if ((unsigned)iy >= 28u) continue;
            for (int sx = 0; sx < 3; sx++) {
                int ix = 2 * xx - 1 + sx;
                if ((unsigned)ix >= 28u) continue;
                acc += w1[c * 9 + sy * 3 + sx] * xb[iy * 28 + ix];
            }
        }
        h1[o] = fmaxf(acc, 0.f);
    }
    __syncthreads();

    // conv2: 8->16, k3 s2 p1, 14->7, bias+bn+relu (h2 stride 52)
    for (int o = t; o < 16 * 49; o += 512) {
        int c = o / 49, r = o % 49, y = r / 7, xx = r % 7;
        float acc = b2[c];
        for (int ci = 0; ci < 8; ci++) {
            for (int sy = 0; sy < 3; sy++) {
                int iy = 2 * y - 1 + sy;
                if ((unsigned)iy >= 14u) continue;
                for (int sx = 0; sx < 3; sx++) {
                    int ix = 2 * xx - 1 + sx;
                    if ((unsigned)ix >= 14u) continue;
                    acc += w2[((c * 8 + ci) * 3 + sy) * 3 + sx] * h1[ci * 196 + iy * 14 + ix];
                }
            }
        }
        float s = g2[c] * bnr;
        h2[c * 52 + r] = fmaxf(acc * s + bt2[c], 0.f);
    }
    __syncthreads();

    // conv3: 16->256, k3 s1 p0, 7->5, bias+relu; all 8 waves (even/odd positions)
    {
        int d = t & 255, half = t >> 8;
        float bb = b3[d];
        if (half == 0) conv3_compute<0>(h2, w3T, bb, d, h3hi, h3lo);
        else           conv3_compute<1>(h2, w3T, bb, d, h3hi, h3lo);
    }
    // zero pad rows 25..31
    for (int i = t; i < 7 * 264; i += 512) {
        h3hi[25 * 264 + i] = 0;
        h3lo[25 * 264 + i] = 0;
    }
    __syncthreads();

    // x2_patch_sum partials
    if (t < 256) {
        int pos = t >> 3, ch = t & 7;
        const ushort_t* ph = &h3hi[pos * 264 + ch * 32];
        const ushort_t* pl = &h3lo[pos * 264 + ch * 32];
        float s = 0.f;
#pragma unroll
        for (int i = 0; i < 32; i += 8) {
            us8 vh = *(const us8*)(ph + i);
            us8 vl = *(const us8*)(pl + i);
#pragma unroll
            for (int j = 0; j < 8; j++) {
                float f = bf16_to_f(vh[j]) + bf16_to_f(vl[j]);
                s = fmaf(f, f, s);
            }
        }
        x2part[pos][ch] = s;
    }
    __syncthreads();
    if (t < 32) {
        float s = 1e30f;
        if (t < 25) {
            s = 0.f;
#pragma unroll
            for (int c = 0; c < 8; c++) s += x2part[t][c];
        }
        x2s[t] = s;
    }
    __syncthreads();

    // MFMA distances: xp[32 pos][512 p], wave w handles p-cols [w*64, w*64+64)
    {
        int w = t >> 6, l = t & 63, lr = l & 15, lg = l >> 4;
        f32x4 acc0[4], acc1[4];
#pragma unroll
        for (int i = 0; i < 4; i++) {
            acc0[i] = (f32x4){0.f, 0.f, 0.f, 0.f};
            acc1[i] = (f32x4){0.f, 0.f, 0.f, 0.f};
        }
        const s8v* BH = (const s8v*)pfragHi;
        const s8v* BL = (const s8v*)pfragLo;
        int ntb = w * 4;
#pragma unroll 2
        for (int k0 = 0; k0 < 8; k0++) {
            s8v ah0 = *(const s8v*)&h3hi[lr * 264 + k0 * 32 + lg * 8];
            s8v ah1 = *(const s8v*)&h3hi[(16 + lr) * 264 + k0 * 32 + lg * 8];
            s8v al0 = *(const s8v*)&h3lo[lr * 264 + k0 * 32 + lg * 8];
            s8v al1 = *(const s8v*)&h3lo[(16 + lr) * 264 + k0 * 32 + lg * 8];
#pragma unroll
            for (int n2 = 0; n2 < 4; n2++) {
                s8v bh = BH[((ntb + n2) * 8 + k0) * 64 + l];
                s8v bl = BL[((ntb + n2) * 8 + k0) * 64 + l];
                acc0[n2] = __builtin_amdgcn_mfma_f32_16x16x32_bf16(ah0, bh, acc0[n2], 0, 0, 0);
                acc1[n2] = __builtin_amdgcn_mfma_f32_16x16x32_bf16(ah1, bh, acc1[n2], 0, 0, 0);
                acc0[n2] = __builtin_amdgcn_mfma_f32_16x16x32_bf16(al0, bh, acc0[n2], 0, 0, 0);
                acc1[n2] = __builtin_amdgcn_mfma_f32_16x16x32_bf16(al1, bh, acc1[n2], 0, 0, 0);
                acc0[n2] = __builtin_amdgcn_mfma_f32_16x16x32_bf16(ah0, bl, acc0[n2], 0, 0, 0);
                acc1[n2] = __builtin_amdgcn_mfma_f32_16x16x32_bf16(ah1, bl, acc1[n2], 0, 0, 0);
            }
        }
        float x2r[8];
#pragma unroll
        for (int r = 0; r < 4; r++) {
            x2r[r]     = x2s[lg * 4 + r];
            x2r[4 + r] = x2s[16 + lg * 4 + r];
        }
#pragma unroll
        for (int n2 = 0; n2 < 4; n2++) {
            int pcol = w * 64 + n2 * 16 + lr;
            float p2v = p2[pcol];
            float mm = 1e30f;
#pragma unroll
            for (int r = 0; r < 4; r++) {
                float d0 = fmaxf(x2r[r]     - 2.f * acc0[n2][r] + p2v, 0.f);
                float d1 = fmaxf(x2r[4 + r] - 2.f * acc1[n2][r] + p2v, 0.f);
                mm = fminf(mm, fminf(d0, d1));
            }
            mm = fminf(mm, __shfl_xor(mm, 16));
            mm = fminf(mm, __shfl_xor(mm, 32));
            if (lg == 0) mds[pcol] = mm;
        }
    }
    __syncthreads();

    // softmax over p of (-mind) -> Wsm (bf16)
    float mind = mds[t];
    md_out[b * PC + t] = mind;
    float a = -mind;
    red[t] = a;
    __syncthreads();
    for (int s = 256; s > 0; s >>= 1) {
        if (t < s) red[t] = fmaxf(red[t], red[t + s]);
        __syncthreads();
    }
    float m = red[0];
    __syncthreads();
    float e = expf(a - m);
    red[t] = e;
    __syncthreads();
    for (int s = 256; s > 0; s >>= 1) {
        if (t < s) red[t] += red[t + s];
        __syncthreads();
    }
    float sum = red[0];
    Wsm[(size_t)b * PC + t] = f2bf(e / sum);
}

// ---------------- K2: zupT = Wsm x PW (bf16 MFMA), bias+bn+relu ----------------
__global__ __launch_bounds__(512) void k_zup2(
    const ushort_t* __restrict__ Wsm,      // [4096][512]
    const ushort_t* __restrict__ PWfrag,   // [400][16][64][8]
    const float* __restrict__ bup, const float* __restrict__ gup,
    const float* __restrict__ btup,
    ushort_t* __restrict__ zupT)           // [4096][6400]
{
    int t = threadIdx.x;
    int w = t >> 6, l = t & 63;
    int n0 = blockIdx.x * 128;             // 50
    int m0 = blockIdx.y * 128;             // 32
    int row = m0 + w * 16 + (l & 15);
    int krow = (l >> 4) * 8;
    f32x4 acc[8];
#pragma unroll
    for (int i = 0; i < 8; i++) acc[i] = (f32x4){0.f, 0.f, 0.f, 0.f};
    const s8v* B = (const s8v*)PWfrag;
    int ntb = blockIdx.x * 8;
    for (int k0 = 0; k0 < 16; k0++) {
        s8v a = *(const s8v*)&Wsm[(size_t)row * 512 + k0 * 32 + krow];
#pragma unroll
        for (int nt = 0; nt < 8; nt++) {
            s8v bb = B[((size_t)(ntb + nt) * 16 + k0) * 64 + l];
            acc[nt] = __builtin_amdgcn_mfma_f32_16x16x32_bf16(a, bb, acc[nt], 0, 0, 0);
        }
    }
    const float bnr = rsqrtf(1.0f + 1e-5f);
    int rowbase = m0 + w * 16 + (l >> 4) * 4;
#pragma unroll
    for (int nt = 0; nt < 8; nt++) {
        int n = n0 + nt * 16 + (l & 15);
        int ch = n & 255;
        float sc = gup[ch] * bnr, bb = bup[ch], bt = btup[ch];
#pragma unroll
        for (int r = 0; r < 4; r++) {
            float v = (acc[nt][r] + bb) * sc + bt;
            zupT[(size_t)(rowbase + r) * 6400 + n] = f2bf(fmaxf(v, 0.f));
        }
    }
}

// ---------------- K3: P[102400][144] = zupT[102400][256] x wd1 (bf16 MFMA) ----------------
__global__ __launch_bounds__(256) void k_dgemm(
    const ushort_t* __restrict__ zupT,
    const ushort_t* __restrict__ wd1frag,  // [9][8][64][8]
    float* __restrict__ P)
{
    int t = threadIdx.x;
    int w = t >> 6, l = t & 63;
    int r0 = blockIdx.x * 64 + w * 16;     // 1600 blocks
    int krow = (l >> 4) * 8;
    f32x4 acc[9];
#pragma unroll
    for (int i = 0; i < 9; i++) acc[i] = (f32x4){0.f, 0.f, 0.f, 0.f};
    const s8v* B = (const s8v*)wd1frag;
#pragma unroll
    for (int k0 = 0; k0 < 8; k0++) {
        s8v a = *(const s8v*)&zupT[(size_t)(r0 + (l & 15)) * 256 + k0 * 32 + krow];
#pragma unroll
        for (int nt = 0; nt < 9; nt++) {
            s8v bb = B[(nt * 8 + k0) * 64 + l];
            acc[nt] = __builtin_amdgcn_mfma_f32_16x16x32_bf16(a, bb, acc[nt], 0, 0, 0);
        }
    }
    int rowbase = r0 + (l >> 4) * 4;
#pragma unroll
    for (int nt = 0; nt < 9; nt++) {
        int n = nt * 16 + (l & 15);
#pragma unroll
        for (int r = 0; r < 4; r++)
            P[(size_t)(rowbase + r) * 144 + n] = acc[nt][r];
    }
}

// ---------------- K4: gather wd1 + wd2 + wd3 + sigmoid, one block per image ----------------
__global__ __launch_bounds__(256) void k_dtail(
    const float* __restrict__ P,
    const float* __restrict__ bd1, const float* __restrict__ gd1, const float* __restrict__ btd1,
    const float* __restrict__ wd2, const float* __restrict__ bd2,
    const float* __restrict__ gd2, const float* __restrict__ btd2,
    const float* __restrict__ wd3, const float* __restrict__ bd3,
    float* __restrict__ out0)
{
    int b = blockIdx.x, t = threadIdx.x;
    __shared__ float Ps[25][148];
    __shared__ float hd1s[16 * 49];
    __shared__ float hd2s[8 * 196];
    __shared__ float w2s[1152];
    __shared__ float w3s[72];

    const float bnr = rsqrtf(1.0f + 1e-5f);

    const float* Pg = P + (size_t)b * 3600;
    for (int i = t; i < 3600; i += 256) Ps[i / 144][i % 144] = Pg[i];
    for (int i = t; i < 1152; i += 256) w2s[i] = wd2[i];
    if (t < 72) w3s[t] = wd3[t];
    __syncthreads();

    for (int o = t; o < 784; o += 256) {
        int co = o / 49, rr = o % 49, y = rr / 7, xx = rr % 7;
        float a = bd1[co];
        int sy0 = y - 4 > 0 ? y - 4 : 0, sy1 = y < 2 ? y : 2;
        for (int sy = sy0; sy <= sy1; sy++) {
            int iy = y - sy;
            int sx0 = xx - 4 > 0 ? xx - 4 : 0, sx1 = xx < 2 ? xx : 2;
            for (int sx = sx0; sx <= sx1; sx++) {
                int ix = xx - sx;
                a += Ps[iy * 5 + ix][co * 9 + sy * 3 + sx];
            }
        }
        float v = a * (gd1[co] * bnr) + btd1[co];
        hd1s[o] = fmaxf(v, 0.f);
    }
    __syncthreads();

    for (int o = t; o < 8 * 196; o += 256) {
        int co = o / 196, r = o % 196, y = r / 14, xx = r % 14;
        float a = 0.f;
        for (int sy = 0; sy < 3; sy++) {
            int yn = y + 1 - sy;
            if (yn & 1) continue;
            int iy = yn >> 1;
            if ((unsigned)iy >= 7u) continue;
            for (int sx = 0; sx < 3; sx++) {
                int xn = xx + 1 - sx;
                if (xn & 1) continue;
                int ix = xn >> 1;
                if ((unsigned)ix >= 7u) continue;
                for (int ci = 0; ci < 16; ci++)
                    a += w2s[(ci * 8 + co) * 9 + sy * 3 + sx] * hd1s[ci * 49 + iy * 7 + ix];
            }
        }
        float v = (a + bd2[co]) * (gd2[co] * bnr) + btd2[co];
        hd2s[o] = fmaxf(v, 0.f);
    }
    __syncthreads();

    float* og = out0 + b * 784;
    for (int o = t; o < 784; o += 256) {
        int y = o / 28, xx = o % 28;
        float a = bd3[0];
        for (int sy = 0; sy < 3; sy++) {
            int yn = y + 1 - sy;
            if (yn & 1) continue;
            int iy = yn >> 1;
            if ((unsigned)iy >= 14u) continue;
            for (int sx = 0; sx < 3; sx++) {
                int xn = xx + 1 - sx;
                if (xn & 1) continue;
                int ix = xn >> 1;
                if ((unsigned)ix >= 14u) continue;
                for (int ci = 0; ci < 8; ci++)
                    a += w3s[ci * 9 + sy * 3 + sx] * hd2s[ci * 196 + iy * 14 + ix];
            }
        }
        og[o] = 1.f / (1.f + expf(-a));
    }
}

extern "C" void kernel_launch(void* const* d_in, const int* in_sizes, int n_in,
                              void* d_out, int out_size, void* d_ws, size_t ws_size,
                              hipStream_t stream) {
    const float* x    = (const float*)d_in[0];
    const float* w1   = (const float*)d_in[1];
    const float* b1   = (const float*)d_in[2];
    const float* w2   = (const float*)d_in[3];
    const float* b2   = (const float*)d_in[4];
    const float* g2   = (const float*)d_in[5];
    const float* bt2  = (const float*)d_in[6];
    const float* w3   = (const float*)d_in[7];
    const float* b3   = (const float*)d_in[8];
    const float* proto= (const float*)d_in[9];
    const float* wup  = (const float*)d_in[10];
    const float* bup  = (const float*)d_in[11];
    const float* gup  = (const float*)d_in[12];
    const float* btup = (const float*)d_in[13];
    const float* wd1  = (const float*)d_in[14];
    const float* bd1  = (const float*)d_in[15];
    const float* gd1  = (const float*)d_in[16];
    const float* btd1 = (const float*)d_in[17];
    const float* wd2  = (const float*)d_in[18];
    const float* bd2  = (const float*)d_in[19];
    const float* gd2  = (const float*)d_in[20];
    const float* btd2 = (const float*)d_in[21];
    const float* wd3  = (const float*)d_in[22];
    const float* bd3  = (const float*)d_in[23];

    float* out0   = (float*)d_out;                 // [4096][784]
    float* out_md = out0 + (size_t)NB * 784;       // [4096][512]

    // ws layout
    float*    p2      = (float*)d_ws;                          // 512 f
    ushort_t* pfragHi = (ushort_t*)(p2 + 512);                 // 131072
    ushort_t* pfragLo = pfragHi + 131072;                      // 131072
    float*    w3T     = (float*)(pfragLo + 131072);            // 36864 f
    ushort_t* wd1frag = (ushort_t*)(w3T + 36864);              // 36864
    ushort_t* zupT    = wd1frag + 36864;                       // 26,214,400
    ushort_t* Wsm     = zupT + (size_t)26214400;               // 2,097,152
    ushort_t* PWfrag  = Wsm + 2097152;                         // 3,276,800
    float*    P       = (float*)Wsm;                           // 102400*144 f (aliases Wsm/PWfrag; both dead)

    hipLaunchKernelGGL(k_prep, dim3(PC), dim3(256), 0, stream, proto, p2);
    hipLaunchKernelGGL(k_pack, dim3(512), dim3(256), 0, stream, proto, pfragHi, pfragLo);
    hipLaunchKernelGGL(k_w3t, dim3(144), dim3(256), 0, stream, w3, w3T);
    hipLaunchKernelGGL(k_wd1p, dim3(144), dim3(256), 0, stream, wd1, wd1frag);
    hipLaunchKernelGGL(k_pw, dim3(100, 8), dim3(256), 0, stream, proto, wup, PWfrag);
    hipLaunchKernelGGL(k_enc_proto, dim3(NB), dim3(512), 0, stream,
                       x, w1, b1, w2, b2, g2, bt2, w3T, b3,
                       pfragHi, pfragLo, p2, out_md, Wsm);
    hipLaunchKernelGGL(k_zup2, dim3(50, 32), dim3(512), 0, stream,
                       Wsm, PWfrag, bup, gup, btup, zupT);
    hipLaunchKernelGGL(k_dgemm, dim3(1600), dim3(256), 0, stream, zupT, wd1frag, P);
    hipLaunchKernelGGL(k_dtail, dim3(NB), dim3(256), 0, stream,
                       P, bd1, gd1, btd1, wd2, bd2, gd2, btd2, wd3, bd3, out0);
}

// Round 5
// 526.998 us; speedup vs baseline: 3.4029x; 1.2306x over previous
//
#include <hip/hip_runtime.h>
#include <hip/hip_bf16.h>
#include <math.h>

#define NB 4096
#define DC 256
#define PC 512

typedef unsigned short ushort_t;
typedef __attribute__((ext_vector_type(8))) unsigned short us8;
typedef __attribute__((ext_vector_type(8))) short s8v;       // bf16x8 for MFMA
typedef __attribute__((ext_vector_type(4))) float f32x4;

__device__ __forceinline__ float bf16_to_f(ushort_t u) {
    union { unsigned int i; float f; } c;
    c.i = ((unsigned int)u) << 16;
    return c.f;
}
__device__ __forceinline__ ushort_t f2bf(float f) {          // RNE
    union { float f; unsigned int u; } c; c.f = f;
    unsigned int r = c.u + 0x7fffu + ((c.u >> 16) & 1u);
    return (ushort_t)(r >> 16);
}

// ---------------- K0: p2 ----------------
__global__ __launch_bounds__(256) void k_prep(const float* __restrict__ proto,
                                              float* __restrict__ p2) {
    int p = blockIdx.x;       // 0..511
    int d = threadIdx.x;      // 0..255
    float v = proto[p * DC + d];
    __shared__ float red[256];
    red[d] = v * v;
    __syncthreads();
    for (int s = 128; s > 0; s >>= 1) {
        if (d < s) red[d] += red[d + s];
        __syncthreads();
    }
    if (d == 0) p2[p] = red[0];
}

// ---------------- K0a: pack proto into MFMA B-fragment layout, bf16 hi/lo ----------------
// frag[((nt*8 + k0)*64 + lane)*8 + j], n = nt*16 + (lane&15), k = k0*32 + (lane>>4)*8 + j
__global__ __launch_bounds__(256) void k_pack(const float* __restrict__ proto,
                                              ushort_t* __restrict__ pfragHi,
                                              ushort_t* __restrict__ pfragLo) {
    int idx = blockIdx.x * 256 + threadIdx.x;   // 512 blocks -> 131072
    int j  = idx & 7;
    int l  = (idx >> 3) & 63;
    int k0 = (idx >> 9) & 7;
    int nt = idx >> 12;
    int n = nt * 16 + (l & 15);
    int k = k0 * 32 + (l >> 4) * 8 + j;
    float v = proto[n * DC + k];
    ushort_t hi = f2bf(v);
    pfragHi[idx] = hi;
    pfragLo[idx] = f2bf(v - bf16_to_f(hi));
}

// ---------------- K0c: pack w3 -> B-fragments hi/lo [16 nt][5 k0][64][8], zero for k>=144 ----
__global__ __launch_bounds__(256) void k_w3p(const float* __restrict__ w3,
                                             ushort_t* __restrict__ w3fH,
                                             ushort_t* __restrict__ w3fL) {
    int idx = blockIdx.x * 256 + threadIdx.x;    // 160 blocks -> 40960
    int j = idx & 7, l = (idx >> 3) & 63;
    int q = idx >> 9;
    int k0 = q % 5, nt = q / 5;
    int d = nt * 16 + (l & 15);
    int k = k0 * 32 + (l >> 4) * 8 + j;
    float v = (k < 144) ? w3[d * 144 + k] : 0.f;
    ushort_t hi = f2bf(v);
    w3fH[idx] = hi;
    w3fL[idx] = f2bf(v - bf16_to_f(hi));
}

// ---------------- K0d: pack wd1 -> bf16 B-fragments [9 nt][8 k0][64][8] ----------------
__global__ __launch_bounds__(256) void k_wd1p(const float* __restrict__ wd1,
                                              ushort_t* __restrict__ wd1frag) {
    int idx = blockIdx.x * 256 + threadIdx.x;   // 144 blocks -> 36864
    int j  = idx & 7;
    int l  = (idx >> 3) & 63;
    int k0 = (idx >> 9) & 7;
    int nt = idx >> 12;                          // 0..8
    int n = nt * 16 + (l & 15);                  // 0..143
    int k = k0 * 32 + (l >> 4) * 8 + j;          // 0..255
    wd1frag[idx] = f2bf(wd1[k * 144 + n]);
}

// ---------------- K0e: PW = proto x wupT, stored as bf16 B-fragments for k_zup2 ----------
__global__ __launch_bounds__(256) void k_pw(
    const float* __restrict__ proto,   // [512][256]
    const float* __restrict__ wup,     // [256][6400] native cols = ch*25+pos
    ushort_t* __restrict__ PWfrag)
{
    __shared__ float As[32 * 65];
    __shared__ float Bs[32 * 64];
    int t = threadIdx.x;
    int n0 = blockIdx.x * 64;          // native col
    int m0 = blockIdx.y * 64;          // p
    int tx = t % 16, ty = t / 16;
    float acc[4][4];
#pragma unroll
    for (int i = 0; i < 4; i++)
#pragma unroll
        for (int j = 0; j < 4; j++) acc[i][j] = 0.f;

    for (int k0 = 0; k0 < 256; k0 += 32) {
        for (int i = t; i < 2048; i += 256) {
            int m = i / 32, k = i % 32;
            As[k * 65 + m] = proto[(m0 + m) * 256 + k0 + k];
        }
        for (int i = t; i < 2048; i += 256) {
            int k = i / 64, n = i % 64;
            Bs[k * 64 + n] = wup[(k0 + k) * 6400 + n0 + n];
        }
        __syncthreads();
#pragma unroll 8
        for (int k = 0; k < 32; k++) {
            float a0 = As[k * 65 + ty], a1 = As[k * 65 + ty + 16];
            float a2 = As[k * 65 + ty + 32], a3 = As[k * 65 + ty + 48];
            float b0 = Bs[k * 64 + tx], b1 = Bs[k * 64 + tx + 16];
            float b2 = Bs[k * 64 + tx + 32], b3 = Bs[k * 64 + tx + 48];
            acc[0][0] += a0 * b0; acc[0][1] += a0 * b1; acc[0][2] += a0 * b2; acc[0][3] += a0 * b3;
            acc[1][0] += a1 * b0; acc[1][1] += a1 * b1; acc[1][2] += a1 * b2; acc[1][3] += a1 * b3;
            acc[2][0] += a2 * b0; acc[2][1] += a2 * b1; acc[2][2] += a2 * b2; acc[2][3] += a2 * b3;
            acc[3][0] += a3 * b0; acc[3][1] += a3 * b1; acc[3][2] += a3 * b2; acc[3][3] += a3 * b3;
        }
        __syncthreads();
    }

#pragma unroll
    for (int i = 0; i < 4; i++) {
#pragma unroll
        for (int j = 0; j < 4; j++) {
            int p  = m0 + ty + 16 * i;
            int nn = n0 + tx + 16 * j;           // native
            int ch = nn / 25, pos = nn % 25;
            int np = pos * 256 + ch;             // n'
            int nt = np >> 4, k0p = p >> 5;
            int ll = ((p >> 3) & 3) * 16 + (np & 15);
            int jj = p & 7;
            PWfrag[(((nt * 16 + k0p) * 64) + ll) * 8 + jj] = f2bf(acc[i][j]);
        }
    }
}

// ---------------- K1: encoder convs (conv3 via MFMA) + MFMA distances + softmax -> Wsm ----
__global__ __launch_bounds__(512) void k_enc_proto(
    const float* __restrict__ x,
    const float* __restrict__ w1, const float* __restrict__ b1,
    const float* __restrict__ w2, const float* __restrict__ b2,
    const float* __restrict__ g2, const float* __restrict__ bt2,
    const ushort_t* __restrict__ w3fH, const ushort_t* __restrict__ w3fL,
    const float* __restrict__ b3,
    const ushort_t* __restrict__ pfragHi, const ushort_t* __restrict__ pfragLo,
    const float* __restrict__ p2,
    float* __restrict__ md_out,    // [B][512]
    ushort_t* __restrict__ Wsm)    // [B][512] bf16 softmax weights
{
    int b = blockIdx.x;
    int t = threadIdx.x;

    // one shared buffer, time-multiplexed regions:
    //  [0,9248)      imHi [32][144]+16 pad       (im2col -> conv3)
    //  [9248,18496)  imLo                         (im2col -> conv3)
    //  [18496,52288) h3hi(16896)+h3lo(16896)      (conv3 -> dist)
    //    overlays inside h3 region (dead before conv3 epilogue):
    //    xb@18496(3136) h1@21632(6272) h2@48960(3136)
    //  mds@0 (2048), wred@2048 (64): live only in dist/softmax (im2col dead)
    __shared__ __align__(16) unsigned char buf[52288];
    __shared__ float x2s[32];

    ushort_t* imHi = (ushort_t*)(buf);
    ushort_t* imLo = (ushort_t*)(buf + 9248);
    ushort_t* h3hi = (ushort_t*)(buf + 18496);
    ushort_t* h3lo = (ushort_t*)(buf + 35392);
    float* xb   = (float*)(buf + 18496);
    float* h1   = (float*)(buf + 21632);
    float* h2   = (float*)(buf + 48960);
    float* mds  = (float*)(buf);
    float* wred = (float*)(buf + 2048);

    const float bnr = rsqrtf(1.0f + 1e-5f);
    int w = t >> 6, l = t & 63;
    int lr = l & 15, lg = l >> 4;

    const float* xg = x + b * 784;
    for (int i = t; i < 784; i += 512) xb[i] = xg[i];
    if (t < 32) x2s[t] = (t < 25) ? 0.f : 1e30f;
    __syncthreads();

    // conv1: 1->8, k3 s2 p1, 28->14, bias+relu
    for (int o = t; o < 8 * 196; o += 512) {
        int c = o / 196, r = o % 196, y = r / 14, xx = r % 14;
        float acc = b1[c];
        for (int sy = 0; sy < 3; sy++) {
            int iy = 2 * y - 1 + sy;
            if ((unsigned)iy >= 28u) continue;
            for (int sx = 0; sx < 3; sx++) {
                int ix = 2 * xx - 1 + sx;
                if ((unsigned)ix >= 28u) continue;
                acc += w1[c * 9 + sy * 3 + sx] * xb[iy * 28 + ix];
            }
        }
        h1[o] = fmaxf(acc, 0.f);
    }
    __syncthreads();

    // conv2: 8->16, k3 s2 p1, 14->7, bias+bn+relu
    for (int o = t; o < 16 * 49; o += 512) {
        int c = o / 49, r = o % 49, y = r / 7, xx = r % 7;
        float acc = b2[c];
        for (int ci = 0; ci < 8; ci++) {
            for (int sy = 0; sy < 3; sy++) {
                int iy = 2 * y - 1 + sy;
                if ((unsigned)iy >= 14u) continue;
                for (int sx = 0; sx < 3; sx++) {
                    int ix = 2 * xx - 1 + sx;
                    if ((unsigned)ix >= 14u) continue;
                    acc += w2[((c * 8 + ci) * 3 + sy) * 3 + sx] * h1[ci * 196 + iy * 14 + ix];
                }
            }
        }
        float s = g2[c] * bnr;
        h2[c * 49 + r] = fmaxf(acc * s + bt2[c], 0.f);
    }
    __syncthreads();

    // im2col: patch[pos][k] (k = ci*9+s), bf16 hi/lo; zero rows 25..31 and 16-elem tail
    for (int e = t; e < 3600; e += 512) {
        int pos = e / 144, k = e % 144;
        int ci = k / 9, s = k % 9;
        int sy = s / 3, sx = s % 3;
        int py = pos / 5, px = pos % 5;
        float v = h2[ci * 49 + (py + sy) * 7 + (px + sx)];
        ushort_t hi = f2bf(v);
        imHi[pos * 144 + k] = hi;
        imLo[pos * 144 + k] = f2bf(v - bf16_to_f(hi));
    }
    for (int e = t; e < 1024; e += 512) {        // 7*144+16 = 1024
        imHi[25 * 144 + e] = 0;
        imLo[25 * 144 + e] = 0;
    }
    __syncthreads();

    // conv3 as MFMA: C[32 pos][256 d] = im2col x w3frag (hi/lo 3-term), bias+relu,
    // write h3 hi/lo + x2 via shfl-reduce + LDS atomics
    {
        int nt0 = 2 * w;
        f32x4 c00 = {0,0,0,0}, c01 = {0,0,0,0}, c10 = {0,0,0,0}, c11 = {0,0,0,0};
        const s8v* WH = (const s8v*)w3fH;
        const s8v* WL = (const s8v*)w3fL;
#pragma unroll
        for (int k0 = 0; k0 < 5; k0++) {
            s8v ah0 = *(const s8v*)&imHi[lr * 144 + k0 * 32 + lg * 8];
            s8v ah1 = *(const s8v*)&imHi[(16 + lr) * 144 + k0 * 32 + lg * 8];
            s8v al0 = *(const s8v*)&imLo[lr * 144 + k0 * 32 + lg * 8];
            s8v al1 = *(const s8v*)&imLo[(16 + lr) * 144 + k0 * 32 + lg * 8];
            s8v bh0 = WH[(nt0 * 5 + k0) * 64 + l];
            s8v bl0 = WL[(nt0 * 5 + k0) * 64 + l];
            s8v bh1 = WH[((nt0 + 1) * 5 + k0) * 64 + l];
            s8v bl1 = WL[((nt0 + 1) * 5 + k0) * 64 + l];
            c00 = __builtin_amdgcn_mfma_f32_16x16x32_bf16(ah0, bh0, c00, 0, 0, 0);
            c10 = __builtin_amdgcn_mfma_f32_16x16x32_bf16(ah1, bh0, c10, 0, 0, 0);
            c00 = __builtin_amdgcn_mfma_f32_16x16x32_bf16(al0, bh0, c00, 0, 0, 0);
            c10 = __builtin_amdgcn_mfma_f32_16x16x32_bf16(al1, bh0, c10, 0, 0, 0);
            c00 = __builtin_amdgcn_mfma_f32_16x16x32_bf16(ah0, bl0, c00, 0, 0, 0);
            c10 = __builtin_amdgcn_mfma_f32_16x16x32_bf16(ah1, bl0, c10, 0, 0, 0);
            c01 = __builtin_amdgcn_mfma_f32_16x16x32_bf16(ah0, bh1, c01, 0, 0, 0);
            c11 = __builtin_amdgcn_mfma_f32_16x16x32_bf16(ah1, bh1, c11, 0, 0, 0);
            c01 = __builtin_amdgcn_mfma_f32_16x16x32_bf16(al0, bh1, c01, 0, 0, 0);
            c11 = __builtin_amdgcn_mfma_f32_16x16x32_bf16(al1, bh1, c11, 0, 0, 0);
            c01 = __builtin_amdgcn_mfma_f32_16x16x32_bf16(ah0, bl1, c01, 0, 0, 0);
            c11 = __builtin_amdgcn_mfma_f32_16x16x32_bf16(ah1, bl1, c11, 0, 0, 0);
        }
        // epilogue
#pragma unroll
        for (int q = 0; q < 2; q++) {
            int d = (nt0 + q) * 16 + lr;
            float bb = b3[d];
            f32x4 cm0 = q ? c01 : c00;
            f32x4 cm1 = q ? c11 : c10;
#pragma unroll
            for (int mt = 0; mt < 2; mt++) {
                f32x4 cc = mt ? cm1 : cm0;
#pragma unroll
                for (int r = 0; r < 4; r++) {
                    int pos = mt * 16 + lg * 4 + r;
                    float h = fmaxf(cc[r] + bb, 0.f);
                    ushort_t hi = f2bf(h);
                    h3hi[pos * 264 + d] = hi;
                    h3lo[pos * 264 + d] = f2bf(h - bf16_to_f(hi));
                    float sq = h * h;
                    sq += __shfl_xor(sq, 1);
                    sq += __shfl_xor(sq, 2);
                    sq += __shfl_xor(sq, 4);
                    sq += __shfl_xor(sq, 8);
                    if (lr == 0) atomicAdd(&x2s[pos], sq);
                }
            }
        }
    }
    __syncthreads();

    // MFMA distances: xp[32 pos][512 p], wave w handles p-cols [w*64, w*64+64)
    {
        f32x4 acc0[4], acc1[4];
#pragma unroll
        for (int i = 0; i < 4; i++) {
            acc0[i] = (f32x4){0.f, 0.f, 0.f, 0.f};
            acc1[i] = (f32x4){0.f, 0.f, 0.f, 0.f};
        }
        const s8v* BH = (const s8v*)pfragHi;
        const s8v* BL = (const s8v*)pfragLo;
        int ntb = w * 4;
#pragma unroll 2
        for (int k0 = 0; k0 < 8; k0++) {
            s8v ah0 = *(const s8v*)&h3hi[lr * 264 + k0 * 32 + lg * 8];
            s8v ah1 = *(const s8v*)&h3hi[(16 + lr) * 264 + k0 * 32 + lg * 8];
            s8v al0 = *(const s8v*)&h3lo[lr * 264 + k0 * 32 + lg * 8];
            s8v al1 = *(const s8v*)&h3lo[(16 + lr) * 264 + k0 * 32 + lg * 8];
#pragma unroll
            for (int n2 = 0; n2 < 4; n2++) {
                s8v bh = BH[((ntb + n2) * 8 + k0) * 64 + l];
                s8v bl = BL[((ntb + n2) * 8 + k0) * 64 + l];
                acc0[n2] = __builtin_amdgcn_mfma_f32_16x16x32_bf16(ah0, bh, acc0[n2], 0, 0, 0);
                acc1[n2] = __builtin_amdgcn_mfma_f32_16x16x32_bf16(ah1, bh, acc1[n2], 0, 0, 0);
                acc0[n2] = __builtin_amdgcn_mfma_f32_16x16x32_bf16(al0, bh, acc0[n2], 0, 0, 0);
                acc1[n2] = __builtin_amdgcn_mfma_f32_16x16x32_bf16(al1, bh, acc1[n2], 0, 0, 0);
                acc0[n2] = __builtin_amdgcn_mfma_f32_16x16x32_bf16(ah0, bl, acc0[n2], 0, 0, 0);
                acc1[n2] = __builtin_amdgcn_mfma_f32_16x16x32_bf16(ah1, bl, acc1[n2], 0, 0, 0);
            }
        }
        float x2r[8];
#pragma unroll
        for (int r = 0; r < 4; r++) {
            x2r[r]     = x2s[lg * 4 + r];
            x2r[4 + r] = x2s[16 + lg * 4 + r];
        }
#pragma unroll
        for (int n2 = 0; n2 < 4; n2++) {
            int pcol = w * 64 + n2 * 16 + lr;
            float p2v = p2[pcol];
            float mm = 1e30f;
#pragma unroll
            for (int r = 0; r < 4; r++) {
                float d0 = fmaxf(x2r[r]     - 2.f * acc0[n2][r] + p2v, 0.f);
                float d1 = fmaxf(x2r[4 + r] - 2.f * acc1[n2][r] + p2v, 0.f);
                mm = fminf(mm, fminf(d0, d1));
            }
            mm = fminf(mm, __shfl_xor(mm, 16));
            mm = fminf(mm, __shfl_xor(mm, 32));
            if (lg == 0) mds[pcol] = mm;
        }
    }
    __syncthreads();

    // softmax over p of (-mind), shfl-based
    float mind = mds[t];
    md_out[b * PC + t] = mind;
    float a = -mind;
    float mx = a;
#pragma unroll
    for (int off = 1; off < 64; off <<= 1) mx = fmaxf(mx, __shfl_xor(mx, off));
    if (l == 0) wred[w] = mx;
    __syncthreads();
    float m = wred[0];
#pragma unroll
    for (int i = 1; i < 8; i++) m = fmaxf(m, wred[i]);
    float e = expf(a - m);
    float sm = e;
#pragma unroll
    for (int off = 1; off < 64; off <<= 1) sm += __shfl_xor(sm, off);
    if (l == 0) wred[8 + w] = sm;
    __syncthreads();
    float ssum = wred[8];
#pragma unroll
    for (int i = 9; i < 16; i++) ssum += wred[i];
    Wsm[(size_t)b * PC + t] = f2bf(e / ssum);
}

// ---------------- K2: zupT = Wsm x PW (bf16 MFMA, LDS-staged B), bias+bn+relu ----------------
__global__ __launch_bounds__(512) void k_zup2(
    const ushort_t* __restrict__ Wsm,      // [4096][512]
    const ushort_t* __restrict__ PWfrag,   // [400][16][64][8]
    const float* __restrict__ bup, const float* __restrict__ gup,
    const float* __restrict__ btup,
    ushort_t* __restrict__ zupT)           // [4096][6400]
{
    __shared__ __align__(16) ushort_t Bsh[2][4096];   // 2 x 8KB
    int t = threadIdx.x;
    int w = t >> 6, l = t & 63;
    int n0 = blockIdx.x * 128;             // 50
    int m0 = blockIdx.y * 128;             // 32
    int row = m0 + w * 16 + (l & 15);
    int krow = (l >> 4) * 8;
    f32x4 acc[8];
#pragma unroll
    for (int i = 0; i < 8; i++) acc[i] = (f32x4){0.f, 0.f, 0.f, 0.f};
    const s8v* B = (const s8v*)PWfrag;
    int base = blockIdx.x * 8 * 16;        // ntb*16

    {   // preload k0 = 0 (thread t stages unit t = nt*64+lane)
        s8v b0 = B[(size_t)(base + (t >> 6) * 16) * 64 + (t & 63)];
        *(s8v*)&Bsh[0][t * 8] = b0;
    }
    __syncthreads();
    for (int k0 = 0; k0 < 16; k0++) {
        int cur = k0 & 1;
        if (k0 < 15) {
            s8v bn = B[(size_t)(base + (t >> 6) * 16 + k0 + 1) * 64 + (t & 63)];
            *(s8v*)&Bsh[cur ^ 1][t * 8] = bn;
        }
        s8v a = *(const s8v*)&Wsm[(size_t)row * 512 + k0 * 32 + krow];
#pragma unroll
        for (int nt = 0; nt < 8; nt++) {
            s8v bb = *(const s8v*)&Bsh[cur][(nt * 64 + l) * 8];
            acc[nt] = __builtin_amdgcn_mfma_f32_16x16x32_bf16(a, bb, acc[nt], 0, 0, 0);
        }
        __syncthreads();
    }

    const float bnr = rsqrtf(1.0f + 1e-5f);
    int rowbase = m0 + w * 16 + (l >> 4) * 4;
#pragma unroll
    for (int nt = 0; nt < 8; nt++) {
        int n = n0 + nt * 16 + (l & 15);
        int ch = n & 255;
        float sc = gup[ch] * bnr, bb = bup[ch], bt = btup[ch];
#pragma unroll
        for (int r = 0; r < 4; r++) {
            float v = (acc[nt][r] + bb) * sc + bt;
            zupT[(size_t)(rowbase + r) * 6400 + n] = f2bf(fmaxf(v, 0.f));
        }
    }
}

// ---------------- K3: P[102400][144] = zupT[102400][256] x wd1 (bf16 MFMA) ----------------
__global__ __launch_bounds__(256) void k_dgemm(
    const ushort_t* __restrict__ zupT,
    const ushort_t* __restrict__ wd1frag,  // [9][8][64][8]
    float* __restrict__ P)
{
    int t = threadIdx.x;
    int w = t >> 6, l = t & 63;
    int r0 = blockIdx.x * 64 + w * 16;     // 1600 blocks
    int krow = (l >> 4) * 8;
    f32x4 acc[9];
#pragma unroll
    for (int i = 0; i < 9; i++) acc[i] = (f32x4){0.f, 0.f, 0.f, 0.f};
    const s8v* B = (const s8v*)wd1frag;
#pragma unroll
    for (int k0 = 0; k0 < 8; k0++) {
        s8v a = *(const s8v*)&zupT[(size_t)(r0 + (l & 15)) * 256 + k0 * 32 + krow];
#pragma unroll
        for (int nt = 0; nt < 9; nt++) {
            s8v bb = B[(nt * 8 + k0) * 64 + l];
            acc[nt] = __builtin_amdgcn_mfma_f32_16x16x32_bf16(a, bb, acc[nt], 0, 0, 0);
        }
    }
    int rowbase = r0 + (l >> 4) * 4;
#pragma unroll
    for (int nt = 0; nt < 9; nt++) {
        int n = nt * 16 + (l & 15);
#pragma unroll
        for (int r = 0; r < 4; r++)
            P[(size_t)(rowbase + r) * 144 + n] = acc[nt][r];
    }
}

// ---------------- K4: gather wd1 + wd2 + wd3 + sigmoid, one block per image ----------------
__global__ __launch_bounds__(256) void k_dtail(
    const float* __restrict__ P,
    const float* __restrict__ bd1, const float* __restrict__ gd1, const float* __restrict__ btd1,
    const float* __restrict__ wd2, const float* __restrict__ bd2,
    const float* __restrict__ gd2, const float* __restrict__ btd2,
    const float* __restrict__ wd3, const float* __restrict__ bd3,
    float* __restrict__ out0)
{
    int b = blockIdx.x, t = threadIdx.x;
    __shared__ float Ps[25][148];
    __shared__ float hd1s[16 * 49];
    __shared__ float hd2s[8 * 196];
    __shared__ float w2s[1152];
    __shared__ float w3s[72];

    const float bnr = rsqrtf(1.0f + 1e-5f);

    const float* Pg = P + (size_t)b * 3600;
    for (int i = t; i < 3600; i += 256) Ps[i / 144][i % 144] = Pg[i];
    for (int i = t; i < 1152; i += 256) w2s[i] = wd2[i];
    if (t < 72) w3s[t] = wd3[t];
    __syncthreads();

    for (int o = t; o < 784; o += 256) {
        int co = o / 49, rr = o % 49, y = rr / 7, xx = rr % 7;
        float a = bd1[co];
        int sy0 = y - 4 > 0 ? y - 4 : 0, sy1 = y < 2 ? y : 2;
        for (int sy = sy0; sy <= sy1; sy++) {
            int iy = y - sy;
            int sx0 = xx - 4 > 0 ? xx - 4 : 0, sx1 = xx < 2 ? xx : 2;
            for (int sx = sx0; sx <= sx1; sx++) {
                int ix = xx - sx;
                a += Ps[iy * 5 + ix][co * 9 + sy * 3 + sx];
            }
        }
        float v = a * (gd1[co] * bnr) + btd1[co];
        hd1s[o] = fmaxf(v, 0.f);
    }
    __syncthreads();

    for (int o = t; o < 8 * 196; o += 256) {
        int co = o / 196, r = o % 196, y = r / 14, xx = r % 14;
        float a = 0.f;
        for (int sy = 0; sy < 3; sy++) {
            int yn = y + 1 - sy;
            if (yn & 1) continue;
            int iy = yn >> 1;
            if ((unsigned)iy >= 7u) continue;
            for (int sx = 0; sx < 3; sx++) {
                int xn = xx + 1 - sx;
                if (xn & 1) continue;
                int ix = xn >> 1;
                if ((unsigned)ix >= 7u) continue;
                for (int ci = 0; ci < 16; ci++)
                    a += w2s[(ci * 8 + co) * 9 + sy * 3 + sx] * hd1s[ci * 49 + iy * 7 + ix];
            }
        }
        float v = (a + bd2[co]) * (gd2[co] * bnr) + btd2[co];
        hd2s[o] = fmaxf(v, 0.f);
    }
    __syncthreads();

    float* og = out0 + b * 784;
    for (int o = t; o < 784; o += 256) {
        int y = o / 28, xx = o % 28;
        float a = bd3[0];
        for (int sy = 0; sy < 3; sy++) {
            int yn = y + 1 - sy;
            if (yn & 1) continue;
            int iy = yn >> 1;
            if ((unsigned)iy >= 14u) continue;
            for (int sx = 0; sx < 3; sx++) {
                int xn = xx + 1 - sx;
                if (xn & 1) continue;
                int ix = xn >> 1;
                if ((unsigned)ix >= 14u) continue;
                for (int ci = 0; ci < 8; ci++)
                    a += w3s[ci * 9 + sy * 3 + sx] * hd2s[ci * 196 + iy * 14 + ix];
            }
        }
        og[o] = 1.f / (1.f + expf(-a));
    }
}

extern "C" void kernel_launch(void* const* d_in, const int* in_sizes, int n_in,
                              void* d_out, int out_size, void* d_ws, size_t ws_size,
                              hipStream_t stream) {
    const float* x    = (const float*)d_in[0];
    const float* w1   = (const float*)d_in[1];
    const float* b1   = (const float*)d_in[2];
    const float* w2   = (const float*)d_in[3];
    const float* b2   = (const float*)d_in[4];
    const float* g2   = (const float*)d_in[5];
    const float* bt2  = (const float*)d_in[6];
    const float* w3   = (const float*)d_in[7];
    const float* b3   = (const float*)d_in[8];
    const float* proto= (const float*)d_in[9];
    const float* wup  = (const float*)d_in[10];
    const float* bup  = (const float*)d_in[11];
    const float* gup  = (const float*)d_in[12];
    const float* btup = (const float*)d_in[13];
    const float* wd1  = (const float*)d_in[14];
    const float* bd1  = (const float*)d_in[15];
    const float* gd1  = (const float*)d_in[16];
    const float* btd1 = (const float*)d_in[17];
    const float* wd2  = (const float*)d_in[18];
    const float* bd2  = (const float*)d_in[19];
    const float* gd2  = (const float*)d_in[20];
    const float* btd2 = (const float*)d_in[21];
    const float* wd3  = (const float*)d_in[22];
    const float* bd3  = (const float*)d_in[23];

    float* out0   = (float*)d_out;                 // [4096][784]
    float* out_md = out0 + (size_t)NB * 784;       // [4096][512]

    // ws layout
    float*    p2      = (float*)d_ws;                          // 512 f
    ushort_t* pfragHi = (ushort_t*)(p2 + 512);                 // 131072
    ushort_t* pfragLo = pfragHi + 131072;                      // 131072
    ushort_t* w3fH    = pfragLo + 131072;                      // 40960
    ushort_t* w3fL    = w3fH + 40960;                          // 40960
    ushort_t* wd1frag = w3fL + 40960;                          // 36864
    ushort_t* zupT    = wd1frag + 36864;                       // 26,214,400
    ushort_t* Wsm     = zupT + (size_t)26214400;               // 2,097,152
    ushort_t* PWfrag  = Wsm + 2097152;                         // 3,276,800
    float*    P       = (float*)Wsm;                           // 102400*144 f (aliases Wsm/PWfrag; both dead)

    hipLaunchKernelGGL(k_prep, dim3(PC), dim3(256), 0, stream, proto, p2);
    hipLaunchKernelGGL(k_pack, dim3(512), dim3(256), 0, stream, proto, pfragHi, pfragLo);
    hipLaunchKernelGGL(k_w3p, dim3(160), dim3(256), 0, stream, w3, w3fH, w3fL);
    hipLaunchKernelGGL(k_wd1p, dim3(144), dim3(256), 0, stream, wd1, wd1frag);
    hipLaunchKernelGGL(k_pw, dim3(100, 8), dim3(256), 0, stream, proto, wup, PWfrag);
    hipLaunchKernelGGL(k_enc_proto, dim3(NB), dim3(512), 0, stream,
                       x, w1, b1, w2, b2, g2, bt2, w3fH, w3fL, b3,
                       pfragHi, pfragLo, p2, out_md, Wsm);
    hipLaunchKernelGGL(k_zup2, dim3(50, 32), dim3(512), 0, stream,
                       Wsm, PWfrag, bup, gup, btup, zupT);
    hipLaunchKernelGGL(k_dgemm, dim3(1600), dim3(256), 0, stream, zupT, wd1frag, P);
    hipLaunchKernelGGL(k_dtail, dim3(NB), dim3(256), 0, stream,
                       P, bd1, gd1, btd1, wd2, bd2, gd2, btd2, wd3, bd3, out0);
}